// Round 11
// baseline (1044.525 us; speedup 1.0000x reference)
//
#include <hip/hip_runtime.h>
#include <hip/hip_cooperative_groups.h>

namespace cg = cooperative_groups;

#define N_NODES 20000
#define N_EDGES 640000
#define E_TOT   (N_EDGES + N_NODES)   /* 660000: edges + self loops */
#define IN_DIM  128
#define HIDDEN  256
#define OUT_DIM 64
#define LOG2E 1.4426950408889634f
#define NSHARD 8
#define CSR_BLOCKS 1024
#define CSR_THREADS 256

typedef __attribute__((ext_vector_type(2))) float f32x2;

__device__ __forceinline__ unsigned short f2bf(float f) {
    union { float f; unsigned int i; } x; x.f = f;
    unsigned int u = x.i;
    return (unsigned short)((u + 0x7fffu + ((u >> 16) & 1u)) >> 16);  // RTNE
}
__device__ __forceinline__ f32x2 up2(unsigned int p) {   // 2 packed bf16 -> 2 fp32
    f32x2 r;
    r.x = __uint_as_float(p << 16);
    r.y = __uint_as_float(p & 0xffff0000u);
    return r;
}
__device__ __forceinline__ unsigned int pk2(float a, float b) {
    return (unsigned int)f2bf(a) | ((unsigned int)f2bf(b) << 16);
}

// ---------------- CSR build: ONE cooperative kernel, 6 phases ----------------
// Replaces zero/count/sumdeg/scan/cursor/scatter (R9: 6 launches, ~40 us of
// boundary overhead). grid.sync() between phases. Shard mapping blockIdx&7 is
// IDENTICAL in count and scatter phases (same grid-stride structure) -- the
// per-shard cursor ranges are exact.

__global__ __launch_bounds__(CSR_THREADS) void csr_coop_kernel(
        const int* __restrict__ esrc, const int* __restrict__ edst,
        int* __restrict__ cnt8, int* __restrict__ deg, int* __restrict__ indptr,
        int* __restrict__ bsum, int* __restrict__ ssrc) {
    cg::grid_group grid = cg::this_grid();
    int bid = blockIdx.x, tid = threadIdx.x;
    int gtid = bid * CSR_THREADS + tid;
    const int GT = CSR_BLOCKS * CSR_THREADS;
    int shard = bid & (NSHARD - 1);

    // phase0: zero counters
    for (int i = gtid; i < NSHARD * N_NODES; i += GT) cnt8[i] = 0;
    grid.sync();

    // phase1: sharded degree count
    for (int i = gtid; i < E_TOT; i += GT) {
        int d = (i < N_EDGES) ? edst[i] : (i - N_EDGES);   // implicit self-loop
        atomicAdd(&cnt8[shard * N_NODES + d], 1);
    }
    grid.sync();

    // phase2: deg[i] = sum of 8 shard counts (grid-parallel)
    for (int i = gtid; i < N_NODES; i += GT) {
        int s = 0;
#pragma unroll
        for (int s8 = 0; s8 < NSHARD; s8++) s += cnt8[s8 * N_NODES + i];
        deg[i] = s;
    }
    grid.sync();

    // phase3a: block-local scan. Blocks 0..999 each own 20 nodes (exact).
    if (bid < 1000 && tid < 32) {
        int idx = bid * 20 + tid;
        int v = (tid < 20) ? deg[idx] : 0;
        int x = v;
#pragma unroll
        for (int off = 1; off < 32; off <<= 1) {
            int y = __shfl_up(x, off);
            if (tid >= off) x += y;
        }
        if (tid == 19) bsum[bid] = x;    // block total
    }
    grid.sync();

    // phase3b: block 0 scans the 1000 block totals -> exclusive prefixes in place
    if (bid == 0) {
        __shared__ int sm[CSR_THREADS];
        int base = tid * 4;
        int l0 = 0, l1 = 0, l2 = 0, l3 = 0;
        if (base < 1000) {
            l0 = bsum[base];
            l1 = (base + 1 < 1000) ? bsum[base + 1] : 0;
            l2 = (base + 2 < 1000) ? bsum[base + 2] : 0;
            l3 = (base + 3 < 1000) ? bsum[base + 3] : 0;
        }
        int tot = l0 + l1 + l2 + l3;
        sm[tid] = tot;
        __syncthreads();
        for (int off = 1; off < CSR_THREADS; off <<= 1) {
            int v = (tid >= off) ? sm[tid - off] : 0;
            __syncthreads();
            sm[tid] += v;
            __syncthreads();
        }
        int pre = (tid == 0) ? 0 : sm[tid - 1];
        if (base < 1000) {
            bsum[base] = pre;
            if (base + 1 < 1000) bsum[base + 1] = pre + l0;
            if (base + 2 < 1000) bsum[base + 2] = pre + l0 + l1;
            if (base + 3 < 1000) bsum[base + 3] = pre + l0 + l1 + l2;
        }
        if (tid == CSR_THREADS - 1) bsum[1000] = sm[CSR_THREADS - 1];  // == E_TOT
    }
    grid.sync();

    // phase3c: indptr = block prefix + local exclusive (recompute local scan)
    if (bid < 1000 && tid < 32) {
        int idx = bid * 20 + tid;
        int v = (tid < 20) ? deg[idx] : 0;
        int x = v;
#pragma unroll
        for (int off = 1; off < 32; off <<= 1) {
            int y = __shfl_up(x, off);
            if (tid >= off) x += y;
        }
        if (tid < 20) indptr[idx] = bsum[bid] + x - v;
    }
    if (gtid == 0) indptr[N_NODES] = bsum[1000];
    grid.sync();

    // phase4: rewrite cnt8 into absolute scatter cursors (grid-parallel)
    for (int i = gtid; i < N_NODES; i += GT) {
        int running = indptr[i];
#pragma unroll
        for (int s8 = 0; s8 < NSHARD; s8++) {
            int c = cnt8[s8 * N_NODES + i];
            cnt8[s8 * N_NODES + i] = running;
            running += c;
        }
    }
    grid.sync();

    // phase5: sharded edge scatter (same i->shard mapping as phase1)
    for (int i = gtid; i < E_TOT; i += GT) {
        int d, s;
        if (i < N_EDGES) { d = edst[i]; s = esrc[i]; }
        else             { d = i - N_EDGES; s = d; }
        int pos = atomicAdd(&cnt8[shard * N_NODES + d], 1);
        ssrc[pos] = s;
    }
}

// ---------------- GEMM1 fused with row-normalize (R9-proven form) ----------------

__global__ __launch_bounds__(256) void gemm1_norm_kernel(const float* __restrict__ A,
                                                         const float* __restrict__ W,
                                                         const float* __restrict__ bias,
                                                         unsigned short* __restrict__ hnb,
                                                         float* __restrict__ r) {
    __shared__ float As[16][20];
    __shared__ float Bs[16][260];
    int t = threadIdx.x;
    int row = t >> 4;
    int cg  = t & 15;
    int grow = blockIdx.x * 16 + row;
    float4 acc0 = make_float4(0.f, 0.f, 0.f, 0.f);
    float4 acc1 = acc0, acc2 = acc0, acc3 = acc0;

    for (int k0 = 0; k0 < IN_DIM; k0 += 16) {
        As[row][cg] = A[(long)grow * IN_DIM + k0 + cg];
        {
            const float4* src = (const float4*)&W[(long)(k0 + row) * HIDDEN];
#pragma unroll
            for (int j = 0; j < 4; j++)
                *((float4*)&Bs[row][4 * cg + 64 * j]) = src[cg + 16 * j];
        }
        __syncthreads();
#pragma unroll
        for (int kk = 0; kk < 16; kk++) {
            float a = As[row][kk];
            float4 q0 = *((const float4*)&Bs[kk][4 * cg]);
            float4 q1 = *((const float4*)&Bs[kk][4 * cg + 64]);
            float4 q2 = *((const float4*)&Bs[kk][4 * cg + 128]);
            float4 q3 = *((const float4*)&Bs[kk][4 * cg + 192]);
            acc0.x += a * q0.x; acc0.y += a * q0.y; acc0.z += a * q0.z; acc0.w += a * q0.w;
            acc1.x += a * q1.x; acc1.y += a * q1.y; acc1.z += a * q1.z; acc1.w += a * q1.w;
            acc2.x += a * q2.x; acc2.y += a * q2.y; acc2.z += a * q2.z; acc2.w += a * q2.w;
            acc3.x += a * q3.x; acc3.y += a * q3.y; acc3.z += a * q3.z; acc3.w += a * q3.w;
        }
        __syncthreads();
    }

    float ss = 0.f;
    {
        float4 bv = *((const float4*)&bias[4 * cg]);
        acc0.x = fmaxf(acc0.x + bv.x, 0.f); acc0.y = fmaxf(acc0.y + bv.y, 0.f);
        acc0.z = fmaxf(acc0.z + bv.z, 0.f); acc0.w = fmaxf(acc0.w + bv.w, 0.f);
        ss += acc0.x * acc0.x + acc0.y * acc0.y + acc0.z * acc0.z + acc0.w * acc0.w;
    }
    {
        float4 bv = *((const float4*)&bias[4 * cg + 64]);
        acc1.x = fmaxf(acc1.x + bv.x, 0.f); acc1.y = fmaxf(acc1.y + bv.y, 0.f);
        acc1.z = fmaxf(acc1.z + bv.z, 0.f); acc1.w = fmaxf(acc1.w + bv.w, 0.f);
        ss += acc1.x * acc1.x + acc1.y * acc1.y + acc1.z * acc1.z + acc1.w * acc1.w;
    }
    {
        float4 bv = *((const float4*)&bias[4 * cg + 128]);
        acc2.x = fmaxf(acc2.x + bv.x, 0.f); acc2.y = fmaxf(acc2.y + bv.y, 0.f);
        acc2.z = fmaxf(acc2.z + bv.z, 0.f); acc2.w = fmaxf(acc2.w + bv.w, 0.f);
        ss += acc2.x * acc2.x + acc2.y * acc2.y + acc2.z * acc2.z + acc2.w * acc2.w;
    }
    {
        float4 bv = *((const float4*)&bias[4 * cg + 192]);
        acc3.x = fmaxf(acc3.x + bv.x, 0.f); acc3.y = fmaxf(acc3.y + bv.y, 0.f);
        acc3.z = fmaxf(acc3.z + bv.z, 0.f); acc3.w = fmaxf(acc3.w + bv.w, 0.f);
        ss += acc3.x * acc3.x + acc3.y * acc3.y + acc3.z * acc3.z + acc3.w * acc3.w;
    }
    ss += __shfl_xor(ss, 1);
    ss += __shfl_xor(ss, 2);
    ss += __shfl_xor(ss, 4);
    ss += __shfl_xor(ss, 8);
    float rr = sqrtf(ss + 1e-12f);
    float ir = 1.f / rr;
    uint2* dst = (uint2*)(hnb + (long)grow * HIDDEN);
    uint2 o;
    o.x = pk2(acc0.x * ir, acc0.y * ir); o.y = pk2(acc0.z * ir, acc0.w * ir);
    dst[cg]      = o;
    o.x = pk2(acc1.x * ir, acc1.y * ir); o.y = pk2(acc1.z * ir, acc1.w * ir);
    dst[cg + 16] = o;
    o.x = pk2(acc2.x * ir, acc2.y * ir); o.y = pk2(acc2.z * ir, acc2.w * ir);
    dst[cg + 32] = o;
    o.x = pk2(acc3.x * ir, acc3.y * ir); o.y = pk2(acc3.z * ir, acc3.w * ir);
    dst[cg + 48] = o;
    if (cg == 0) r[grow] = rr;
}

// ---------------- fp32 tiled GEMM + bias (GEMM2, R3-proven form) ----------------

__global__ __launch_bounds__(256) void gemm_bias_act(const float* __restrict__ A,
                                                     const float* __restrict__ B,
                                                     const float* __restrict__ bias,
                                                     float* __restrict__ C,
                                                     int M, int Nn, int K, int relu) {
    __shared__ float As[16][65];
    __shared__ float Bs[16][65];
    int tid = threadIdx.x;
    int tx = tid & 15, ty = tid >> 4;
    int row0 = blockIdx.x * 64, col0 = blockIdx.y * 64;
    float acc[4][4] = {};
    for (int k0 = 0; k0 < K; k0 += 16) {
        {
            int r_ = tid >> 2;
            int kq = (tid & 3) * 4;
            int gr = row0 + r_;
            float4 a4 = make_float4(0.f, 0.f, 0.f, 0.f);
            if (gr < M) a4 = *(const float4*)&A[(long)gr * K + k0 + kq];
            As[kq + 0][r_] = a4.x; As[kq + 1][r_] = a4.y;
            As[kq + 2][r_] = a4.z; As[kq + 3][r_] = a4.w;
        }
        {
            int kr = tid >> 4;
            int cq = (tid & 15) * 4;
            float4 b4 = *(const float4*)&B[(long)(k0 + kr) * Nn + col0 + cq];
            Bs[kr][cq + 0] = b4.x; Bs[kr][cq + 1] = b4.y;
            Bs[kr][cq + 2] = b4.z; Bs[kr][cq + 3] = b4.w;
        }
        __syncthreads();
#pragma unroll
        for (int kk = 0; kk < 16; kk++) {
            float a[4], b[4];
#pragma unroll
            for (int i = 0; i < 4; i++) a[i] = As[kk][ty * 4 + i];
#pragma unroll
            for (int j = 0; j < 4; j++) b[j] = Bs[kk][tx * 4 + j];
#pragma unroll
            for (int i = 0; i < 4; i++)
#pragma unroll
                for (int j = 0; j < 4; j++) acc[i][j] += a[i] * b[j];
        }
        __syncthreads();
    }
#pragma unroll
    for (int i = 0; i < 4; i++) {
        int gr = row0 + ty * 4 + i;
        if (gr >= M) continue;
#pragma unroll
        for (int j = 0; j < 4; j++) {
            int gc = col0 + tx * 4 + j;
            float v = acc[i][j] + bias[gc];
            if (relu) v = fmaxf(v, 0.f);
            C[(long)gr * Nn + gc] = v;
        }
    }
}

// ---------------- fused AGNN layer (R9-proven form: guarded prefetch) ----------------

__global__ __launch_bounds__(256) void agnn_kernel(const unsigned short* __restrict__ hnb,
                                                   const float* __restrict__ rin,
                                                   const int* __restrict__ indptr,
                                                   const int* __restrict__ ssrc,
                                                   unsigned short* __restrict__ hnout,
                                                   float* __restrict__ rout,
                                                   float* __restrict__ hout,
                                                   int write_hn) {
    int lane = threadIdx.x & 63;
    int wid  = threadIdx.x >> 6;
    int sub  = lane >> 4;          // which quarter of the edge list (0..3)
    int gl   = lane & 15;          // lane in 16-group
    int node = blockIdx.x * 4 + wid;   // grid exact: 5000*4 = 20000

    const uint4* tab4 = (const uint4*)hnb;   // one uint4 = 8 bf16; row = 32 uint4
    long nb = (long)node * 32 + gl * 2;
    uint4 ha = tab4[nb], hb = tab4[nb + 1];
    f32x2 hd2[8];
    hd2[0] = up2(ha.x) * LOG2E; hd2[1] = up2(ha.y) * LOG2E;
    hd2[2] = up2(ha.z) * LOG2E; hd2[3] = up2(ha.w) * LOG2E;
    hd2[4] = up2(hb.x) * LOG2E; hd2[5] = up2(hb.y) * LOG2E;
    hd2[6] = up2(hb.z) * LOG2E; hd2[7] = up2(hb.w) * LOG2E;

    int beg = indptr[node], end = indptr[node + 1];
    int deg = end - beg;               // >= 1 (self loop)
    int qb  = deg >> 2, rem = deg & 3;
    int cnt = qb + (sub < rem ? 1 : 0);
    int eb  = beg + sub * qb + min(sub, rem);
    int nmax = qb + (rem ? 1 : 0);     // uniform wave loop bound

    f32x2 acc[8];
#pragma unroll
    for (int p = 0; p < 8; p++) acc[p] = (f32x2)0.f;
    float z = 0.f;

    // guarded 3-deep pipeline prologue
    int s0 = ssrc[(cnt > 0) ? eb : beg];
    long b0 = (long)s0 * 32 + gl * 2;
    uint4 v0a = tab4[b0], v0b = tab4[b0 + 1];
    float r0 = rin[s0];
    uint4 v1a = v0a, v1b = v0b;        // finite defaults for masked tails
    float r1 = 0.f;
    int s2 = s0;
    if (cnt >= 2) {
        int s1 = ssrc[eb + 1];
        long b1 = (long)s1 * 32 + gl * 2;
        v1a = tab4[b1]; v1b = tab4[b1 + 1];
        r1 = rin[s1];
    }
    if (cnt >= 3) s2 = ssrc[eb + 2];

    for (int i = 0; i < nmax; i++) {
        uint4 ca = v0a, cb = v0b;
        float cr = r0;
        v0a = v1a; v0b = v1b; r0 = r1;
        if (i + 2 < cnt) {             // group-uniform guard: no wasted gathers
            long b2 = (long)s2 * 32 + gl * 2;
            v1a = tab4[b2]; v1b = tab4[b2 + 1];
            r1 = rin[s2];
        }
        if (i + 3 < cnt) s2 = ssrc[eb + i + 3];

        f32x2 cf[8];
        cf[0] = up2(ca.x); cf[1] = up2(ca.y); cf[2] = up2(ca.z); cf[3] = up2(ca.w);
        cf[4] = up2(cb.x); cf[5] = up2(cb.y); cf[6] = up2(cb.z); cf[7] = up2(cb.w);
        f32x2 da = cf[0] * hd2[0];
        f32x2 db = cf[1] * hd2[1];
        da += cf[2] * hd2[2];  db += cf[3] * hd2[3];
        da += cf[4] * hd2[4];  db += cf[5] * hd2[5];
        da += cf[6] * hd2[6];  db += cf[7] * hd2[7];
        f32x2 d2 = da + db;
        float d = d2.x + d2.y;
        d += __shfl_xor(d, 1);
        d += __shfl_xor(d, 2);
        d += __shfl_xor(d, 4);
        d += __shfl_xor(d, 8);
        float w = (i < cnt) ? exp2f(d) : 0.f;   // mask tail of shorter streams
        z += w;
        float wr = w * cr;
#pragma unroll
        for (int p = 0; p < 8; p++) acc[p] += cf[p] * wr;
    }

    // merge the 4 partial streams (plain sums -- no max state)
    z += __shfl_xor(z, 16);
    z += __shfl_xor(z, 32);
#pragma unroll
    for (int p = 0; p < 8; p++) {
        acc[p].x += __shfl_xor(acc[p].x, 16);
        acc[p].y += __shfl_xor(acc[p].y, 16);
        acc[p].x += __shfl_xor(acc[p].x, 32);
        acc[p].y += __shfl_xor(acc[p].y, 32);
    }

    float inv = 1.f / z;
    f32x2 o[8];
#pragma unroll
    for (int p = 0; p < 8; p++) {
        f32x2 t = acc[p] * inv;
        t.x = fmaxf(t.x, 0.f);
        t.y = fmaxf(t.y, 0.f);
        o[p] = t;
    }

    if (write_hn) {
        float ss = 0.f;
#pragma unroll
        for (int p = 0; p < 8; p++) ss += o[p].x * o[p].x + o[p].y * o[p].y;
        ss += __shfl_xor(ss, 1);
        ss += __shfl_xor(ss, 2);
        ss += __shfl_xor(ss, 4);
        ss += __shfl_xor(ss, 8);     // full row lives in each 16-lane group
        float rr = sqrtf(ss + 1e-12f);
        float ir = 1.f / rr;
        if (sub == 0) {
            uint4 oa, ob;
            oa.x = pk2(o[0].x * ir, o[0].y * ir);
            oa.y = pk2(o[1].x * ir, o[1].y * ir);
            oa.z = pk2(o[2].x * ir, o[2].y * ir);
            oa.w = pk2(o[3].x * ir, o[3].y * ir);
            ob.x = pk2(o[4].x * ir, o[4].y * ir);
            ob.y = pk2(o[5].x * ir, o[5].y * ir);
            ob.z = pk2(o[6].x * ir, o[6].y * ir);
            ob.w = pk2(o[7].x * ir, o[7].y * ir);
            uint4* outt = (uint4*)hnout;
            outt[nb] = oa;
            outt[nb + 1] = ob;
            if (gl == 0) rout[node] = rr;
        }
    } else {
        if (sub == 0) {
            float4* ho = (float4*)(hout + (long)node * HIDDEN + gl * 16);
            ho[0] = make_float4(o[0].x, o[0].y, o[1].x, o[1].y);
            ho[1] = make_float4(o[2].x, o[2].y, o[3].x, o[3].y);
            ho[2] = make_float4(o[4].x, o[4].y, o[5].x, o[5].y);
            ho[3] = make_float4(o[6].x, o[6].y, o[7].x, o[7].y);
        }
    }
}

// ---------------- launch (7 kernels) ----------------

extern "C" void kernel_launch(void* const* d_in, const int* in_sizes, int n_in,
                              void* d_out, int out_size, void* d_ws, size_t ws_size,
                              hipStream_t stream) {
    const float* x  = (const float*)d_in[0];
    const int* esrc = (const int*)d_in[1];
    const int* edst = (const int*)d_in[2];
    const float* W1 = (const float*)d_in[3];
    const float* b1 = (const float*)d_in[4];
    const float* W2 = (const float*)d_in[5];
    const float* b2 = (const float*)d_in[6];
    float* out = (float*)d_out;

    char* ws = (char*)d_ws;
    float*          h0     = (float*)(ws);                          // 20,480,000 B
    unsigned short* hnA    = (unsigned short*)(ws + 20480000);      // 10,240,000 B
    unsigned short* hnB    = (unsigned short*)(ws + 30720000);      // 10,240,000 B
    float*          rA     = (float*)(ws + 40960000);               // 80,000 B
    float*          rB     = (float*)(ws + 41040000);               // 80,000 B
    int*            indptr = (int*)  (ws + 41120000);               // 80,004 B (pad)
    int*            cnt8   = (int*)  (ws + 41200256);               // 640,000 B
    int*            ssrc   = (int*)  (ws + 41840256);               // 2,640,000 B
    int*            deg    = (int*)  (ws + 44480256);               // 80,000 B
    int*            bsum   = (int*)  (ws + 44560256);               // 4,004 B

    {
        void* args[] = { (void*)&esrc, (void*)&edst, (void*)&cnt8, (void*)&deg,
                         (void*)&indptr, (void*)&bsum, (void*)&ssrc };
        hipLaunchCooperativeKernel((void*)csr_coop_kernel,
                                   dim3(CSR_BLOCKS), dim3(CSR_THREADS),
                                   args, 0, stream);
    }

    gemm1_norm_kernel<<<N_NODES / 16, 256, 0, stream>>>(x, W1, b1, hnA, rA);

    int nblk = N_NODES / 4;   // 5000, exact
    // L0: A -> B, L1: B -> A, L2: A -> B, L3: B -> h0 (fp32)
    agnn_kernel<<<nblk, 256, 0, stream>>>(hnA, rA, indptr, ssrc, hnB, rB, h0, 1);
    agnn_kernel<<<nblk, 256, 0, stream>>>(hnB, rB, indptr, ssrc, hnA, rA, h0, 1);
    agnn_kernel<<<nblk, 256, 0, stream>>>(hnA, rA, indptr, ssrc, hnB, rB, h0, 1);
    agnn_kernel<<<nblk, 256, 0, stream>>>(hnB, rB, indptr, ssrc, hnA, rA, h0, 0);

    dim3 g2((N_NODES + 63) / 64, OUT_DIM / 64);
    gemm_bias_act<<<g2, 256, 0, stream>>>(h0, W2, b2, out, N_NODES, OUT_DIM, HIDDEN, 0);
}

// Round 12
// 329.810 us; speedup vs baseline: 3.1671x; 3.1671x over previous
//
#include <hip/hip_runtime.h>

#define N_NODES 20000
#define N_EDGES 640000
#define E_TOT   (N_EDGES + N_NODES)   /* 660000: edges + self loops */
#define IN_DIM  128
#define HIDDEN  256
#define OUT_DIM 64
#define LOG2E 1.4426950408889634f
#define NOCT   8                      /* src-id octants (s/2500) */
#define NXCD   8                      /* blockIdx&7 ~ XCD id */
#define NSH    (NOCT * NXCD)          /* 64 shards */

typedef __attribute__((ext_vector_type(2))) float f32x2;

__device__ __forceinline__ unsigned short f2bf(float f) {
    union { float f; unsigned int i; } x; x.f = f;
    unsigned int u = x.i;
    return (unsigned short)((u + 0x7fffu + ((u >> 16) & 1u)) >> 16);  // RTNE
}
__device__ __forceinline__ f32x2 up2(unsigned int p) {   // 2 packed bf16 -> 2 fp32
    f32x2 r;
    r.x = __uint_as_float(p << 16);
    r.y = __uint_as_float(p & 0xffff0000u);
    return r;
}
__device__ __forceinline__ unsigned int pk2(float a, float b) {
    return (unsigned int)f2bf(a) | ((unsigned int)f2bf(b) << 16);
}

// ---------------- CSR build (6 kernels; 64 shards = src-octant x XCD) ----------------
// Inner shard index bid&7 is XCD-aligned (R6: kills atomic line ping-pong).
// Outer index = src/2500 makes each node's final edge list GROUPED BY SRC RANGE,
// so agnn's concurrent gathers walk the hn table octant-by-octant (1.28 MB
// per octant -> L2-resident on every XCD) instead of randomly.

__global__ void zero_cnt_kernel(int* __restrict__ cnt) {
    int i = blockIdx.x * blockDim.x + threadIdx.x;
    if (i < NSH * N_NODES) cnt[i] = 0;
}

__global__ void count_kernel(const int* __restrict__ edge_src,
                             const int* __restrict__ edge_dst,
                             int* __restrict__ cnt) {
    int i = blockIdx.x * blockDim.x + threadIdx.x;
    if (i >= E_TOT) return;
    int xcd = blockIdx.x & (NXCD - 1);
    int d, s;
    if (i < N_EDGES) { d = edge_dst[i]; s = edge_src[i]; }
    else             { d = i - N_EDGES; s = d; }
    int shard = (s / 2500) * NXCD + xcd;
    atomicAdd(&cnt[shard * N_NODES + d], 1);
}

__global__ void sumdeg_kernel(const int* __restrict__ cnt, int* __restrict__ deg) {
    int i = blockIdx.x * blockDim.x + threadIdx.x;
    if (i >= N_NODES) return;
    int s = 0;
#pragma unroll
    for (int s8 = 0; s8 < NSH; s8++) s += cnt[s8 * N_NODES + i];
    deg[i] = s;
}

__global__ __launch_bounds__(1024) void scan1b_kernel(const int* __restrict__ deg,
                                                      int* __restrict__ indptr) {
    const int T = 1024;
    const int C = (N_NODES + T - 1) / T;   // 20 per thread
    __shared__ int sums[T];
    int t = threadIdx.x;
    int base = t * C;
    int local[C];
    int s = 0;
#pragma unroll
    for (int i = 0; i < C; i++) {
        int idx = base + i;
        int v = (idx < N_NODES) ? deg[idx] : 0;
        local[i] = s;
        s += v;
    }
    sums[t] = s;
    __syncthreads();
    for (int off = 1; off < T; off <<= 1) {
        int v = (t >= off) ? sums[t - off] : 0;
        __syncthreads();
        sums[t] += v;
        __syncthreads();
    }
    int prefix = (t == 0) ? 0 : sums[t - 1];
#pragma unroll
    for (int i = 0; i < C; i++) {
        int idx = base + i;
        if (idx < N_NODES) indptr[idx] = prefix + local[i];
    }
    if (t == T - 1) indptr[N_NODES] = prefix + s;   // == E_TOT
}

__global__ void cursor_kernel(const int* __restrict__ indptr, int* __restrict__ cnt) {
    int i = blockIdx.x * blockDim.x + threadIdx.x;
    if (i >= N_NODES) return;
    int running = indptr[i];
#pragma unroll
    for (int s8 = 0; s8 < NSH; s8++) {
        int c = cnt[s8 * N_NODES + i];
        cnt[s8 * N_NODES + i] = running;
        running += c;
    }
}

__global__ void scatter_edges_kernel(const int* __restrict__ edge_src,
                                     const int* __restrict__ edge_dst,
                                     int* __restrict__ cnt,
                                     int* __restrict__ ssrc) {
    int i = blockIdx.x * blockDim.x + threadIdx.x;
    if (i >= E_TOT) return;
    int xcd = blockIdx.x & (NXCD - 1);
    int d, s;
    if (i < N_EDGES) { d = edge_dst[i]; s = edge_src[i]; }
    else             { d = i - N_EDGES; s = d; }
    int shard = (s / 2500) * NXCD + xcd;   // same mapping as count
    int pos = atomicAdd(&cnt[shard * N_NODES + d], 1);
    ssrc[pos] = s;
}

// ---------------- GEMM1 fused with row-normalize (R9-proven form) ----------------

__global__ __launch_bounds__(256) void gemm1_norm_kernel(const float* __restrict__ A,
                                                         const float* __restrict__ W,
                                                         const float* __restrict__ bias,
                                                         unsigned short* __restrict__ hnb,
                                                         float* __restrict__ r) {
    __shared__ float As[16][20];
    __shared__ float Bs[16][260];
    int t = threadIdx.x;
    int row = t >> 4;
    int cg  = t & 15;
    int grow = blockIdx.x * 16 + row;
    float4 acc0 = make_float4(0.f, 0.f, 0.f, 0.f);
    float4 acc1 = acc0, acc2 = acc0, acc3 = acc0;

    for (int k0 = 0; k0 < IN_DIM; k0 += 16) {
        As[row][cg] = A[(long)grow * IN_DIM + k0 + cg];
        {
            const float4* src = (const float4*)&W[(long)(k0 + row) * HIDDEN];
#pragma unroll
            for (int j = 0; j < 4; j++)
                *((float4*)&Bs[row][4 * cg + 64 * j]) = src[cg + 16 * j];
        }
        __syncthreads();
#pragma unroll
        for (int kk = 0; kk < 16; kk++) {
            float a = As[row][kk];
            float4 q0 = *((const float4*)&Bs[kk][4 * cg]);
            float4 q1 = *((const float4*)&Bs[kk][4 * cg + 64]);
            float4 q2 = *((const float4*)&Bs[kk][4 * cg + 128]);
            float4 q3 = *((const float4*)&Bs[kk][4 * cg + 192]);
            acc0.x += a * q0.x; acc0.y += a * q0.y; acc0.z += a * q0.z; acc0.w += a * q0.w;
            acc1.x += a * q1.x; acc1.y += a * q1.y; acc1.z += a * q1.z; acc1.w += a * q1.w;
            acc2.x += a * q2.x; acc2.y += a * q2.y; acc2.z += a * q2.z; acc2.w += a * q2.w;
            acc3.x += a * q3.x; acc3.y += a * q3.y; acc3.z += a * q3.z; acc3.w += a * q3.w;
        }
        __syncthreads();
    }

    float ss = 0.f;
    {
        float4 bv = *((const float4*)&bias[4 * cg]);
        acc0.x = fmaxf(acc0.x + bv.x, 0.f); acc0.y = fmaxf(acc0.y + bv.y, 0.f);
        acc0.z = fmaxf(acc0.z + bv.z, 0.f); acc0.w = fmaxf(acc0.w + bv.w, 0.f);
        ss += acc0.x * acc0.x + acc0.y * acc0.y + acc0.z * acc0.z + acc0.w * acc0.w;
    }
    {
        float4 bv = *((const float4*)&bias[4 * cg + 64]);
        acc1.x = fmaxf(acc1.x + bv.x, 0.f); acc1.y = fmaxf(acc1.y + bv.y, 0.f);
        acc1.z = fmaxf(acc1.z + bv.z, 0.f); acc1.w = fmaxf(acc1.w + bv.w, 0.f);
        ss += acc1.x * acc1.x + acc1.y * acc1.y + acc1.z * acc1.z + acc1.w * acc1.w;
    }
    {
        float4 bv = *((const float4*)&bias[4 * cg + 128]);
        acc2.x = fmaxf(acc2.x + bv.x, 0.f); acc2.y = fmaxf(acc2.y + bv.y, 0.f);
        acc2.z = fmaxf(acc2.z + bv.z, 0.f); acc2.w = fmaxf(acc2.w + bv.w, 0.f);
        ss += acc2.x * acc2.x + acc2.y * acc2.y + acc2.z * acc2.z + acc2.w * acc2.w;
    }
    {
        float4 bv = *((const float4*)&bias[4 * cg + 192]);
        acc3.x = fmaxf(acc3.x + bv.x, 0.f); acc3.y = fmaxf(acc3.y + bv.y, 0.f);
        acc3.z = fmaxf(acc3.z + bv.z, 0.f); acc3.w = fmaxf(acc3.w + bv.w, 0.f);
        ss += acc3.x * acc3.x + acc3.y * acc3.y + acc3.z * acc3.z + acc3.w * acc3.w;
    }
    ss += __shfl_xor(ss, 1);
    ss += __shfl_xor(ss, 2);
    ss += __shfl_xor(ss, 4);
    ss += __shfl_xor(ss, 8);
    float rr = sqrtf(ss + 1e-12f);
    float ir = 1.f / rr;
    uint2* dst = (uint2*)(hnb + (long)grow * HIDDEN);
    uint2 o;
    o.x = pk2(acc0.x * ir, acc0.y * ir); o.y = pk2(acc0.z * ir, acc0.w * ir);
    dst[cg]      = o;
    o.x = pk2(acc1.x * ir, acc1.y * ir); o.y = pk2(acc1.z * ir, acc1.w * ir);
    dst[cg + 16] = o;
    o.x = pk2(acc2.x * ir, acc2.y * ir); o.y = pk2(acc2.z * ir, acc2.w * ir);
    dst[cg + 32] = o;
    o.x = pk2(acc3.x * ir, acc3.y * ir); o.y = pk2(acc3.z * ir, acc3.w * ir);
    dst[cg + 48] = o;
    if (cg == 0) r[grow] = rr;
}

// ---------------- fp32 tiled GEMM + bias (GEMM2, R3-proven form) ----------------

__global__ __launch_bounds__(256) void gemm_bias_act(const float* __restrict__ A,
                                                     const float* __restrict__ B,
                                                     const float* __restrict__ bias,
                                                     float* __restrict__ C,
                                                     int M, int Nn, int K, int relu) {
    __shared__ float As[16][65];
    __shared__ float Bs[16][65];
    int tid = threadIdx.x;
    int tx = tid & 15, ty = tid >> 4;
    int row0 = blockIdx.x * 64, col0 = blockIdx.y * 64;
    float acc[4][4] = {};
    for (int k0 = 0; k0 < K; k0 += 16) {
        {
            int r_ = tid >> 2;
            int kq = (tid & 3) * 4;
            int gr = row0 + r_;
            float4 a4 = make_float4(0.f, 0.f, 0.f, 0.f);
            if (gr < M) a4 = *(const float4*)&A[(long)gr * K + k0 + kq];
            As[kq + 0][r_] = a4.x; As[kq + 1][r_] = a4.y;
            As[kq + 2][r_] = a4.z; As[kq + 3][r_] = a4.w;
        }
        {
            int kr = tid >> 4;
            int cq = (tid & 15) * 4;
            float4 b4 = *(const float4*)&B[(long)(k0 + kr) * Nn + col0 + cq];
            Bs[kr][cq + 0] = b4.x; Bs[kr][cq + 1] = b4.y;
            Bs[kr][cq + 2] = b4.z; Bs[kr][cq + 3] = b4.w;
        }
        __syncthreads();
#pragma unroll
        for (int kk = 0; kk < 16; kk++) {
            float a[4], b[4];
#pragma unroll
            for (int i = 0; i < 4; i++) a[i] = As[kk][ty * 4 + i];
#pragma unroll
            for (int j = 0; j < 4; j++) b[j] = Bs[kk][tx * 4 + j];
#pragma unroll
            for (int i = 0; i < 4; i++)
#pragma unroll
                for (int j = 0; j < 4; j++) acc[i][j] += a[i] * b[j];
        }
        __syncthreads();
    }
#pragma unroll
    for (int i = 0; i < 4; i++) {
        int gr = row0 + ty * 4 + i;
        if (gr >= M) continue;
#pragma unroll
        for (int j = 0; j < 4; j++) {
            int gc = col0 + tx * 4 + j;
            float v = acc[i][j] + bias[gc];
            if (relu) v = fmaxf(v, 0.f);
            C[(long)gr * Nn + gc] = v;
        }
    }
}

// ---------------- fused AGNN layer (R9-proven form: guarded prefetch) ----------------

__global__ __launch_bounds__(256) void agnn_kernel(const unsigned short* __restrict__ hnb,
                                                   const float* __restrict__ rin,
                                                   const int* __restrict__ indptr,
                                                   const int* __restrict__ ssrc,
                                                   unsigned short* __restrict__ hnout,
                                                   float* __restrict__ rout,
                                                   float* __restrict__ hout,
                                                   int write_hn) {
    int lane = threadIdx.x & 63;
    int wid  = threadIdx.x >> 6;
    int sub  = lane >> 4;          // which quarter of the edge list (0..3)
    int gl   = lane & 15;          // lane in 16-group
    int node = blockIdx.x * 4 + wid;   // grid exact: 5000*4 = 20000

    const uint4* tab4 = (const uint4*)hnb;   // one uint4 = 8 bf16; row = 32 uint4
    long nb = (long)node * 32 + gl * 2;
    uint4 ha = tab4[nb], hb = tab4[nb + 1];
    f32x2 hd2[8];
    hd2[0] = up2(ha.x) * LOG2E; hd2[1] = up2(ha.y) * LOG2E;
    hd2[2] = up2(ha.z) * LOG2E; hd2[3] = up2(ha.w) * LOG2E;
    hd2[4] = up2(hb.x) * LOG2E; hd2[5] = up2(hb.y) * LOG2E;
    hd2[6] = up2(hb.z) * LOG2E; hd2[7] = up2(hb.w) * LOG2E;

    int beg = indptr[node], end = indptr[node + 1];
    int deg = end - beg;               // >= 1 (self loop)
    int qb  = deg >> 2, rem = deg & 3;
    int cnt = qb + (sub < rem ? 1 : 0);
    int eb  = beg + sub * qb + min(sub, rem);
    int nmax = qb + (rem ? 1 : 0);     // uniform wave loop bound

    f32x2 acc[8];
#pragma unroll
    for (int p = 0; p < 8; p++) acc[p] = (f32x2)0.f;
    float z = 0.f;

    // guarded 3-deep pipeline prologue
    int s0 = ssrc[(cnt > 0) ? eb : beg];
    long b0 = (long)s0 * 32 + gl * 2;
    uint4 v0a = tab4[b0], v0b = tab4[b0 + 1];
    float r0 = rin[s0];
    uint4 v1a = v0a, v1b = v0b;        // finite defaults for masked tails
    float r1 = 0.f;
    int s2 = s0;
    if (cnt >= 2) {
        int s1 = ssrc[eb + 1];
        long b1 = (long)s1 * 32 + gl * 2;
        v1a = tab4[b1]; v1b = tab4[b1 + 1];
        r1 = rin[s1];
    }
    if (cnt >= 3) s2 = ssrc[eb + 2];

    for (int i = 0; i < nmax; i++) {
        uint4 ca = v0a, cb = v0b;
        float cr = r0;
        v0a = v1a; v0b = v1b; r0 = r1;
        if (i + 2 < cnt) {             // group-uniform guard: no wasted gathers
            long b2 = (long)s2 * 32 + gl * 2;
            v1a = tab4[b2]; v1b = tab4[b2 + 1];
            r1 = rin[s2];
        }
        if (i + 3 < cnt) s2 = ssrc[eb + i + 3];

        f32x2 cf[8];
        cf[0] = up2(ca.x); cf[1] = up2(ca.y); cf[2] = up2(ca.z); cf[3] = up2(ca.w);
        cf[4] = up2(cb.x); cf[5] = up2(cb.y); cf[6] = up2(cb.z); cf[7] = up2(cb.w);
        f32x2 da = cf[0] * hd2[0];
        f32x2 db = cf[1] * hd2[1];
        da += cf[2] * hd2[2];  db += cf[3] * hd2[3];
        da += cf[4] * hd2[4];  db += cf[5] * hd2[5];
        da += cf[6] * hd2[6];  db += cf[7] * hd2[7];
        f32x2 d2 = da + db;
        float d = d2.x + d2.y;
        d += __shfl_xor(d, 1);
        d += __shfl_xor(d, 2);
        d += __shfl_xor(d, 4);
        d += __shfl_xor(d, 8);
        float w = (i < cnt) ? exp2f(d) : 0.f;   // mask tail of shorter streams
        z += w;
        float wr = w * cr;
#pragma unroll
        for (int p = 0; p < 8; p++) acc[p] += cf[p] * wr;
    }

    // merge the 4 partial streams (plain sums -- no max state)
    z += __shfl_xor(z, 16);
    z += __shfl_xor(z, 32);
#pragma unroll
    for (int p = 0; p < 8; p++) {
        acc[p].x += __shfl_xor(acc[p].x, 16);
        acc[p].y += __shfl_xor(acc[p].y, 16);
        acc[p].x += __shfl_xor(acc[p].x, 32);
        acc[p].y += __shfl_xor(acc[p].y, 32);
    }

    float inv = 1.f / z;
    f32x2 o[8];
#pragma unroll
    for (int p = 0; p < 8; p++) {
        f32x2 t = acc[p] * inv;
        t.x = fmaxf(t.x, 0.f);
        t.y = fmaxf(t.y, 0.f);
        o[p] = t;
    }

    if (write_hn) {
        float ss = 0.f;
#pragma unroll
        for (int p = 0; p < 8; p++) ss += o[p].x * o[p].x + o[p].y * o[p].y;
        ss += __shfl_xor(ss, 1);
        ss += __shfl_xor(ss, 2);
        ss += __shfl_xor(ss, 4);
        ss += __shfl_xor(ss, 8);     // full row lives in each 16-lane group
        float rr = sqrtf(ss + 1e-12f);
        float ir = 1.f / rr;
        if (sub == 0) {
            uint4 oa, ob;
            oa.x = pk2(o[0].x * ir, o[0].y * ir);
            oa.y = pk2(o[1].x * ir, o[1].y * ir);
            oa.z = pk2(o[2].x * ir, o[2].y * ir);
            oa.w = pk2(o[3].x * ir, o[3].y * ir);
            ob.x = pk2(o[4].x * ir, o[4].y * ir);
            ob.y = pk2(o[5].x * ir, o[5].y * ir);
            ob.z = pk2(o[6].x * ir, o[6].y * ir);
            ob.w = pk2(o[7].x * ir, o[7].y * ir);
            uint4* outt = (uint4*)hnout;
            outt[nb] = oa;
            outt[nb + 1] = ob;
            if (gl == 0) rout[node] = rr;
        }
    } else {
        if (sub == 0) {
            float4* ho = (float4*)(hout + (long)node * HIDDEN + gl * 16);
            ho[0] = make_float4(o[0].x, o[0].y, o[1].x, o[1].y);
            ho[1] = make_float4(o[2].x, o[2].y, o[3].x, o[3].y);
            ho[2] = make_float4(o[4].x, o[4].y, o[5].x, o[5].y);
            ho[3] = make_float4(o[6].x, o[6].y, o[7].x, o[7].y);
        }
    }
}

// ---------------- launch (12 kernels) ----------------

extern "C" void kernel_launch(void* const* d_in, const int* in_sizes, int n_in,
                              void* d_out, int out_size, void* d_ws, size_t ws_size,
                              hipStream_t stream) {
    const float* x  = (const float*)d_in[0];
    const int* esrc = (const int*)d_in[1];
    const int* edst = (const int*)d_in[2];
    const float* W1 = (const float*)d_in[3];
    const float* b1 = (const float*)d_in[4];
    const float* W2 = (const float*)d_in[5];
    const float* b2 = (const float*)d_in[6];
    float* out = (float*)d_out;

    char* ws = (char*)d_ws;
    float*          h0     = (float*)(ws);                          // 20,480,000 B
    unsigned short* hnA    = (unsigned short*)(ws + 20480000);      // 10,240,000 B
    unsigned short* hnB    = (unsigned short*)(ws + 30720000);      // 10,240,000 B
    float*          rA     = (float*)(ws + 40960000);               // 80,000 B
    float*          rB     = (float*)(ws + 41040000);               // 80,000 B
    int*            indptr = (int*)  (ws + 41120000);               // 80,004 B (pad)
    int*            cnt    = (int*)  (ws + 41200256);               // 5,120,000 B (64 shards)
    int*            ssrc   = (int*)  (ws + 46320256);               // 2,640,000 B
    int*            deg    = (int*)  (ws + 48960256);               // 80,000 B

    zero_cnt_kernel<<<(NSH * N_NODES + 255) / 256, 256, 0, stream>>>(cnt);
    count_kernel<<<(E_TOT + 255) / 256, 256, 0, stream>>>(esrc, edst, cnt);
    sumdeg_kernel<<<(N_NODES + 255) / 256, 256, 0, stream>>>(cnt, deg);
    scan1b_kernel<<<1, 1024, 0, stream>>>(deg, indptr);
    cursor_kernel<<<(N_NODES + 255) / 256, 256, 0, stream>>>(indptr, cnt);
    scatter_edges_kernel<<<(E_TOT + 255) / 256, 256, 0, stream>>>(esrc, edst, cnt, ssrc);

    gemm1_norm_kernel<<<N_NODES / 16, 256, 0, stream>>>(x, W1, b1, hnA, rA);

    int nblk = N_NODES / 4;   // 5000, exact
    // L0: A -> B, L1: B -> A, L2: A -> B, L3: B -> h0 (fp32)
    agnn_kernel<<<nblk, 256, 0, stream>>>(hnA, rA, indptr, ssrc, hnB, rB, h0, 1);
    agnn_kernel<<<nblk, 256, 0, stream>>>(hnB, rB, indptr, ssrc, hnA, rA, h0, 1);
    agnn_kernel<<<nblk, 256, 0, stream>>>(hnA, rA, indptr, ssrc, hnB, rB, h0, 1);
    agnn_kernel<<<nblk, 256, 0, stream>>>(hnB, rB, indptr, ssrc, hnA, rA, h0, 0);

    dim3 g2((N_NODES + 63) / 64, OUT_DIM / 64);
    gemm_bias_act<<<g2, 256, 0, stream>>>(h0, W2, b2, out, N_NODES, OUT_DIM, HIDDEN, 0);
}

// Round 13
// 324.917 us; speedup vs baseline: 3.2147x; 1.0151x over previous
//
#include <hip/hip_runtime.h>

#define N_NODES 20000
#define N_EDGES 640000
#define E_TOT   (N_EDGES + N_NODES)   /* 660000: edges + self loops */
#define IN_DIM  128
#define HIDDEN  256
#define OUT_DIM 64
#define LOG2E 1.4426950408889634f
#define NSHARD 8
#define NBIN 1024

typedef __attribute__((ext_vector_type(2))) float f32x2;

__device__ __forceinline__ unsigned short f2bf(float f) {
    union { float f; unsigned int i; } x; x.f = f;
    unsigned int u = x.i;
    return (unsigned short)((u + 0x7fffu + ((u >> 16) & 1u)) >> 16);  // RTNE
}
__device__ __forceinline__ f32x2 up2(unsigned int p) {   // 2 packed bf16 -> 2 fp32
    f32x2 r;
    r.x = __uint_as_float(p << 16);
    r.y = __uint_as_float(p & 0xffff0000u);
    return r;
}
__device__ __forceinline__ unsigned int pk2(float a, float b) {
    return (unsigned int)f2bf(a) | ((unsigned int)f2bf(b) << 16);
}

// ---------------- CSR build + folded degree-sort (6 kernels, R10 structure) ----------------
// cnt8[s][d]: per-shard counters, shard = blockIdx&7 (~XCD-local lines, R6-proven).
// hist8[s][k]: degree histogram (descending bins), same XCD-sharding discipline.

__global__ void zero_cnt8_kernel(int* __restrict__ cnt8, int* __restrict__ hist8) {
    int i = blockIdx.x * blockDim.x + threadIdx.x;
    if (i < NSHARD * N_NODES) cnt8[i] = 0;
    if (i < NSHARD * NBIN) hist8[i] = 0;
}

__global__ void count_kernel(const int* __restrict__ edge_dst, int* __restrict__ cnt8) {
    int i = blockIdx.x * blockDim.x + threadIdx.x;
    if (i >= E_TOT) return;
    int shard = blockIdx.x & (NSHARD - 1);
    int d = (i < N_EDGES) ? edge_dst[i] : (i - N_EDGES);   // implicit self-loop tail
    atomicAdd(&cnt8[shard * N_NODES + d], 1);
}

// deg[i] = sum of 8 shard counts; also degree histogram (descending, XCD-sharded)
__global__ void sumdeg_kernel(const int* __restrict__ cnt8, int* __restrict__ deg,
                              int* __restrict__ hist8) {
    int i = blockIdx.x * blockDim.x + threadIdx.x;
    if (i >= N_NODES) return;
    int shard = blockIdx.x & (NSHARD - 1);
    int s = 0;
#pragma unroll
    for (int s8 = 0; s8 < NSHARD; s8++) s += cnt8[s8 * N_NODES + i];
    deg[i] = s;
    int key = (NBIN - 1) - ((s > NBIN - 1) ? (NBIN - 1) : s);   // descending degree
    atomicAdd(&hist8[shard * NBIN + key], 1);
}

// single block: (a) scan deg -> indptr (R5-proven, 20 loads/thread);
// (b) convert hist8 into ABSOLUTE perm cursors: base(key,shard) =
//     prefix_over_keys + prefix_over_shards_within_key.
__global__ __launch_bounds__(1024) void scan1b_kernel(const int* __restrict__ deg,
                                                      int* __restrict__ indptr,
                                                      int* __restrict__ hist8) {
    const int T = 1024;
    const int C = (N_NODES + T - 1) / T;   // 20 per thread
    __shared__ int sums[T];
    int t = threadIdx.x;
    int base = t * C;
    int local[C];
    int s = 0;
#pragma unroll
    for (int i = 0; i < C; i++) {
        int idx = base + i;
        int v = (idx < N_NODES) ? deg[idx] : 0;
        local[i] = s;
        s += v;
    }
    sums[t] = s;
    __syncthreads();
    for (int off = 1; off < T; off <<= 1) {
        int v = (t >= off) ? sums[t - off] : 0;
        __syncthreads();
        sums[t] += v;
        __syncthreads();
    }
    int prefix = (t == 0) ? 0 : sums[t - 1];
#pragma unroll
    for (int i = 0; i < C; i++) {
        int idx = base + i;
        if (idx < N_NODES) indptr[idx] = prefix + local[i];
    }
    if (t == T - 1) indptr[N_NODES] = prefix + s;   // == E_TOT
    __syncthreads();
    // (b) hist8 cursors: thread t owns key t (8 reads + 8 writes, NOT R6's deep chain)
    int h[NSHARD];
    int tot = 0;
#pragma unroll
    for (int s8 = 0; s8 < NSHARD; s8++) { h[s8] = hist8[s8 * NBIN + t]; tot += h[s8]; }
    sums[t] = tot;
    __syncthreads();
    for (int off = 1; off < T; off <<= 1) {
        int v = (t >= off) ? sums[t - off] : 0;
        __syncthreads();
        sums[t] += v;
        __syncthreads();
    }
    int running = sums[t] - tot;       // exclusive prefix over keys
#pragma unroll
    for (int s8 = 0; s8 < NSHARD; s8++) {
        hist8[s8 * NBIN + t] = running;
        running += h[s8];
    }
}

// cnt8 -> absolute edge cursors; also scatter perm (same i->shard map as sumdeg)
__global__ void cursor_kernel(const int* __restrict__ indptr, int* __restrict__ cnt8,
                              const int* __restrict__ deg, int* __restrict__ hist8,
                              int* __restrict__ perm) {
    int i = blockIdx.x * blockDim.x + threadIdx.x;
    if (i >= N_NODES) return;
    int running = indptr[i];
#pragma unroll
    for (int s8 = 0; s8 < NSHARD; s8++) {
        int c = cnt8[s8 * N_NODES + i];
        cnt8[s8 * N_NODES + i] = running;
        running += c;
    }
    int shard = blockIdx.x & (NSHARD - 1);
    int dv = deg[i];
    int key = (NBIN - 1) - ((dv > NBIN - 1) ? (NBIN - 1) : dv);
    int pos = atomicAdd(&hist8[shard * NBIN + key], 1);
    perm[pos] = i;
}

__global__ void scatter_edges_kernel(const int* __restrict__ edge_src,
                                     const int* __restrict__ edge_dst,
                                     int* __restrict__ cnt8,
                                     int* __restrict__ ssrc) {
    int i = blockIdx.x * blockDim.x + threadIdx.x;
    if (i >= E_TOT) return;
    int shard = blockIdx.x & (NSHARD - 1);
    int d, s;
    if (i < N_EDGES) { d = edge_dst[i]; s = edge_src[i]; }
    else             { d = i - N_EDGES; s = d; }
    int pos = atomicAdd(&cnt8[shard * N_NODES + d], 1);   // absolute cursor
    ssrc[pos] = s;
}

// ---------------- GEMM1 fused with row-normalize (R9-proven form) ----------------

__global__ __launch_bounds__(256) void gemm1_norm_kernel(const float* __restrict__ A,
                                                         const float* __restrict__ W,
                                                         const float* __restrict__ bias,
                                                         unsigned short* __restrict__ hnb,
                                                         float* __restrict__ r) {
    __shared__ float As[16][20];
    __shared__ float Bs[16][260];
    int t = threadIdx.x;
    int row = t >> 4;
    int cg  = t & 15;
    int grow = blockIdx.x * 16 + row;
    float4 acc0 = make_float4(0.f, 0.f, 0.f, 0.f);
    float4 acc1 = acc0, acc2 = acc0, acc3 = acc0;

    for (int k0 = 0; k0 < IN_DIM; k0 += 16) {
        As[row][cg] = A[(long)grow * IN_DIM + k0 + cg];
        {
            const float4* src = (const float4*)&W[(long)(k0 + row) * HIDDEN];
#pragma unroll
            for (int j = 0; j < 4; j++)
                *((float4*)&Bs[row][4 * cg + 64 * j]) = src[cg + 16 * j];
        }
        __syncthreads();
#pragma unroll
        for (int kk = 0; kk < 16; kk++) {
            float a = As[row][kk];
            float4 q0 = *((const float4*)&Bs[kk][4 * cg]);
            float4 q1 = *((const float4*)&Bs[kk][4 * cg + 64]);
            float4 q2 = *((const float4*)&Bs[kk][4 * cg + 128]);
            float4 q3 = *((const float4*)&Bs[kk][4 * cg + 192]);
            acc0.x += a * q0.x; acc0.y += a * q0.y; acc0.z += a * q0.z; acc0.w += a * q0.w;
            acc1.x += a * q1.x; acc1.y += a * q1.y; acc1.z += a * q1.z; acc1.w += a * q1.w;
            acc2.x += a * q2.x; acc2.y += a * q2.y; acc2.z += a * q2.z; acc2.w += a * q2.w;
            acc3.x += a * q3.x; acc3.y += a * q3.y; acc3.z += a * q3.z; acc3.w += a * q3.w;
        }
        __syncthreads();
    }

    float ss = 0.f;
    {
        float4 bv = *((const float4*)&bias[4 * cg]);
        acc0.x = fmaxf(acc0.x + bv.x, 0.f); acc0.y = fmaxf(acc0.y + bv.y, 0.f);
        acc0.z = fmaxf(acc0.z + bv.z, 0.f); acc0.w = fmaxf(acc0.w + bv.w, 0.f);
        ss += acc0.x * acc0.x + acc0.y * acc0.y + acc0.z * acc0.z + acc0.w * acc0.w;
    }
    {
        float4 bv = *((const float4*)&bias[4 * cg + 64]);
        acc1.x = fmaxf(acc1.x + bv.x, 0.f); acc1.y = fmaxf(acc1.y + bv.y, 0.f);
        acc1.z = fmaxf(acc1.z + bv.z, 0.f); acc1.w = fmaxf(acc1.w + bv.w, 0.f);
        ss += acc1.x * acc1.x + acc1.y * acc1.y + acc1.z * acc1.z + acc1.w * acc1.w;
    }
    {
        float4 bv = *((const float4*)&bias[4 * cg + 128]);
        acc2.x = fmaxf(acc2.x + bv.x, 0.f); acc2.y = fmaxf(acc2.y + bv.y, 0.f);
        acc2.z = fmaxf(acc2.z + bv.z, 0.f); acc2.w = fmaxf(acc2.w + bv.w, 0.f);
        ss += acc2.x * acc2.x + acc2.y * acc2.y + acc2.z * acc2.z + acc2.w * acc2.w;
    }
    {
        float4 bv = *((const float4*)&bias[4 * cg + 192]);
        acc3.x = fmaxf(acc3.x + bv.x, 0.f); acc3.y = fmaxf(acc3.y + bv.y, 0.f);
        acc3.z = fmaxf(acc3.z + bv.z, 0.f); acc3.w = fmaxf(acc3.w + bv.w, 0.f);
        ss += acc3.x * acc3.x + acc3.y * acc3.y + acc3.z * acc3.z + acc3.w * acc3.w;
    }
    ss += __shfl_xor(ss, 1);
    ss += __shfl_xor(ss, 2);
    ss += __shfl_xor(ss, 4);
    ss += __shfl_xor(ss, 8);
    float rr = sqrtf(ss + 1e-12f);
    float ir = 1.f / rr;
    uint2* dst = (uint2*)(hnb + (long)grow * HIDDEN);
    uint2 o;
    o.x = pk2(acc0.x * ir, acc0.y * ir); o.y = pk2(acc0.z * ir, acc0.w * ir);
    dst[cg]      = o;
    o.x = pk2(acc1.x * ir, acc1.y * ir); o.y = pk2(acc1.z * ir, acc1.w * ir);
    dst[cg + 16] = o;
    o.x = pk2(acc2.x * ir, acc2.y * ir); o.y = pk2(acc2.z * ir, acc2.w * ir);
    dst[cg + 32] = o;
    o.x = pk2(acc3.x * ir, acc3.y * ir); o.y = pk2(acc3.z * ir, acc3.w * ir);
    dst[cg + 48] = o;
    if (cg == 0) r[grow] = rr;
}

// ---------------- fp32 tiled GEMM + bias (GEMM2, R3-proven form) ----------------

__global__ __launch_bounds__(256) void gemm_bias_act(const float* __restrict__ A,
                                                     const float* __restrict__ B,
                                                     const float* __restrict__ bias,
                                                     float* __restrict__ C,
                                                     int M, int Nn, int K, int relu) {
    __shared__ float As[16][65];
    __shared__ float Bs[16][65];
    int tid = threadIdx.x;
    int tx = tid & 15, ty = tid >> 4;
    int row0 = blockIdx.x * 64, col0 = blockIdx.y * 64;
    float acc[4][4] = {};
    for (int k0 = 0; k0 < K; k0 += 16) {
        {
            int r_ = tid >> 2;
            int kq = (tid & 3) * 4;
            int gr = row0 + r_;
            float4 a4 = make_float4(0.f, 0.f, 0.f, 0.f);
            if (gr < M) a4 = *(const float4*)&A[(long)gr * K + k0 + kq];
            As[kq + 0][r_] = a4.x; As[kq + 1][r_] = a4.y;
            As[kq + 2][r_] = a4.z; As[kq + 3][r_] = a4.w;
        }
        {
            int kr = tid >> 4;
            int cq = (tid & 15) * 4;
            float4 b4 = *(const float4*)&B[(long)(k0 + kr) * Nn + col0 + cq];
            Bs[kr][cq + 0] = b4.x; Bs[kr][cq + 1] = b4.y;
            Bs[kr][cq + 2] = b4.z; Bs[kr][cq + 3] = b4.w;
        }
        __syncthreads();
#pragma unroll
        for (int kk = 0; kk < 16; kk++) {
            float a[4], b[4];
#pragma unroll
            for (int i = 0; i < 4; i++) a[i] = As[kk][ty * 4 + i];
#pragma unroll
            for (int j = 0; j < 4; j++) b[j] = Bs[kk][tx * 4 + j];
#pragma unroll
            for (int i = 0; i < 4; i++)
#pragma unroll
                for (int j = 0; j < 4; j++) acc[i][j] += a[i] * b[j];
        }
        __syncthreads();
    }
#pragma unroll
    for (int i = 0; i < 4; i++) {
        int gr = row0 + ty * 4 + i;
        if (gr >= M) continue;
#pragma unroll
        for (int j = 0; j < 4; j++) {
            int gc = col0 + tx * 4 + j;
            float v = acc[i][j] + bias[gc];
            if (relu) v = fmaxf(v, 0.f);
            C[(long)gr * Nn + gc] = v;
        }
    }
}

// ---------------- fused AGNN layer (R10 form + degree-balanced perm) ----------------
// Perm assigns 4 equal-degree nodes per block (descending): all 4 waves drain
// together (kills the E[max of 4]/mean ~ 25% idle-wave waste) and big blocks
// schedule first (no stragglers).

__global__ __launch_bounds__(256) void agnn_kernel(const unsigned short* __restrict__ hnb,
                                                   const float* __restrict__ rin,
                                                   const int* __restrict__ indptr,
                                                   const int* __restrict__ ssrc,
                                                   const int* __restrict__ perm,
                                                   unsigned short* __restrict__ hnout,
                                                   float* __restrict__ rout,
                                                   float* __restrict__ hout,
                                                   int write_hn) {
    int lane = threadIdx.x & 63;
    int wid  = threadIdx.x >> 6;
    int sub  = lane >> 4;          // which quarter of the edge list (0..3)
    int gl   = lane & 15;          // lane in 16-group
    int node = perm[blockIdx.x * 4 + wid];   // grid exact: 5000*4 = 20000

    const uint4* tab4 = (const uint4*)hnb;   // one uint4 = 8 bf16; row = 32 uint4
    long nb = (long)node * 32 + gl * 2;
    uint4 ha = tab4[nb], hb = tab4[nb + 1];
    f32x2 hd2[8];
    hd2[0] = up2(ha.x) * LOG2E; hd2[1] = up2(ha.y) * LOG2E;
    hd2[2] = up2(ha.z) * LOG2E; hd2[3] = up2(ha.w) * LOG2E;
    hd2[4] = up2(hb.x) * LOG2E; hd2[5] = up2(hb.y) * LOG2E;
    hd2[6] = up2(hb.z) * LOG2E; hd2[7] = up2(hb.w) * LOG2E;

    int beg = indptr[node], end = indptr[node + 1];
    int deg = end - beg;               // >= 1 (self loop)
    int qb  = deg >> 2, rem = deg & 3;
    int cnt = qb + (sub < rem ? 1 : 0);
    int eb  = beg + sub * qb + min(sub, rem);
    int nmax = qb + (rem ? 1 : 0);     // uniform wave loop bound

    f32x2 acc[8];
#pragma unroll
    for (int p = 0; p < 8; p++) acc[p] = (f32x2)0.f;
    float z = 0.f;

    // guarded 3-deep pipeline prologue
    int s0 = ssrc[(cnt > 0) ? eb : beg];
    long b0 = (long)s0 * 32 + gl * 2;
    uint4 v0a = tab4[b0], v0b = tab4[b0 + 1];
    float r0 = rin[s0];
    uint4 v1a = v0a, v1b = v0b;        // finite defaults for masked tails
    float r1 = 0.f;
    int s2 = s0;
    if (cnt >= 2) {
        int s1 = ssrc[eb + 1];
        long b1 = (long)s1 * 32 + gl * 2;
        v1a = tab4[b1]; v1b = tab4[b1 + 1];
        r1 = rin[s1];
    }
    if (cnt >= 3) s2 = ssrc[eb + 2];

    for (int i = 0; i < nmax; i++) {
        uint4 ca = v0a, cb = v0b;
        float cr = r0;
        v0a = v1a; v0b = v1b; r0 = r1;
        if (i + 2 < cnt) {             // group-uniform guard: no wasted gathers
            long b2 = (long)s2 * 32 + gl * 2;
            v1a = tab4[b2]; v1b = tab4[b2 + 1];
            r1 = rin[s2];
        }
        if (i + 3 < cnt) s2 = ssrc[eb + i + 3];

        f32x2 cf[8];
        cf[0] = up2(ca.x); cf[1] = up2(ca.y); cf[2] = up2(ca.z); cf[3] = up2(ca.w);
        cf[4] = up2(cb.x); cf[5] = up2(cb.y); cf[6] = up2(cb.z); cf[7] = up2(cb.w);
        f32x2 da = cf[0] * hd2[0];
        f32x2 db = cf[1] * hd2[1];
        da += cf[2] * hd2[2];  db += cf[3] * hd2[3];
        da += cf[4] * hd2[4];  db += cf[5] * hd2[5];
        da += cf[6] * hd2[6];  db += cf[7] * hd2[7];
        f32x2 d2 = da + db;
        float d = d2.x + d2.y;
        d += __shfl_xor(d, 1);
        d += __shfl_xor(d, 2);
        d += __shfl_xor(d, 4);
        d += __shfl_xor(d, 8);
        float w = (i < cnt) ? exp2f(d) : 0.f;   // mask tail of shorter streams
        z += w;
        float wr = w * cr;
#pragma unroll
        for (int p = 0; p < 8; p++) acc[p] += cf[p] * wr;
    }

    // merge the 4 partial streams (plain sums -- no max state)
    z += __shfl_xor(z, 16);
    z += __shfl_xor(z, 32);
#pragma unroll
    for (int p = 0; p < 8; p++) {
        acc[p].x += __shfl_xor(acc[p].x, 16);
        acc[p].y += __shfl_xor(acc[p].y, 16);
        acc[p].x += __shfl_xor(acc[p].x, 32);
        acc[p].y += __shfl_xor(acc[p].y, 32);
    }

    float inv = 1.f / z;
    f32x2 o[8];
#pragma unroll
    for (int p = 0; p < 8; p++) {
        f32x2 t = acc[p] * inv;
        t.x = fmaxf(t.x, 0.f);
        t.y = fmaxf(t.y, 0.f);
        o[p] = t;
    }

    if (write_hn) {
        float ss = 0.f;
#pragma unroll
        for (int p = 0; p < 8; p++) ss += o[p].x * o[p].x + o[p].y * o[p].y;
        ss += __shfl_xor(ss, 1);
        ss += __shfl_xor(ss, 2);
        ss += __shfl_xor(ss, 4);
        ss += __shfl_xor(ss, 8);     // full row lives in each 16-lane group
        float rr = sqrtf(ss + 1e-12f);
        float ir = 1.f / rr;
        if (sub == 0) {
            uint4 oa, ob;
            oa.x = pk2(o[0].x * ir, o[0].y * ir);
            oa.y = pk2(o[1].x * ir, o[1].y * ir);
            oa.z = pk2(o[2].x * ir, o[2].y * ir);
            oa.w = pk2(o[3].x * ir, o[3].y * ir);
            ob.x = pk2(o[4].x * ir, o[4].y * ir);
            ob.y = pk2(o[5].x * ir, o[5].y * ir);
            ob.z = pk2(o[6].x * ir, o[6].y * ir);
            ob.w = pk2(o[7].x * ir, o[7].y * ir);
            uint4* outt = (uint4*)hnout;
            outt[nb] = oa;
            outt[nb + 1] = ob;
            if (gl == 0) rout[node] = rr;
        }
    } else {
        if (sub == 0) {
            float4* ho = (float4*)(hout + (long)node * HIDDEN + gl * 16);
            ho[0] = make_float4(o[0].x, o[0].y, o[1].x, o[1].y);
            ho[1] = make_float4(o[2].x, o[2].y, o[3].x, o[3].y);
            ho[2] = make_float4(o[4].x, o[4].y, o[5].x, o[5].y);
            ho[3] = make_float4(o[6].x, o[6].y, o[7].x, o[7].y);
        }
    }
}

// ---------------- launch (12 kernels) ----------------

extern "C" void kernel_launch(void* const* d_in, const int* in_sizes, int n_in,
                              void* d_out, int out_size, void* d_ws, size_t ws_size,
                              hipStream_t stream) {
    const float* x  = (const float*)d_in[0];
    const int* esrc = (const int*)d_in[1];
    const int* edst = (const int*)d_in[2];
    const float* W1 = (const float*)d_in[3];
    const float* b1 = (const float*)d_in[4];
    const float* W2 = (const float*)d_in[5];
    const float* b2 = (const float*)d_in[6];
    float* out = (float*)d_out;

    char* ws = (char*)d_ws;
    float*          h0     = (float*)(ws);                          // 20,480,000 B
    unsigned short* hnA    = (unsigned short*)(ws + 20480000);      // 10,240,000 B
    unsigned short* hnB    = (unsigned short*)(ws + 30720000);      // 10,240,000 B
    float*          rA     = (float*)(ws + 40960000);               // 80,000 B
    float*          rB     = (float*)(ws + 41040000);               // 80,000 B
    int*            indptr = (int*)  (ws + 41120000);               // 80,004 B (pad)
    int*            cnt8   = (int*)  (ws + 41200256);               // 640,000 B
    int*            ssrc   = (int*)  (ws + 41840256);               // 2,640,000 B
    int*            deg    = (int*)  (ws + 44480256);               // 80,000 B
    int*            hist8  = (int*)  (ws + 44560256);               // 32,768 B
    int*            perm   = (int*)  (ws + 44593024);               // 80,000 B

    zero_cnt8_kernel<<<(NSHARD * N_NODES + 255) / 256, 256, 0, stream>>>(cnt8, hist8);
    count_kernel<<<(E_TOT + 255) / 256, 256, 0, stream>>>(edst, cnt8);
    sumdeg_kernel<<<(N_NODES + 255) / 256, 256, 0, stream>>>(cnt8, deg, hist8);
    scan1b_kernel<<<1, 1024, 0, stream>>>(deg, indptr, hist8);
    cursor_kernel<<<(N_NODES + 255) / 256, 256, 0, stream>>>(indptr, cnt8, deg, hist8, perm);
    scatter_edges_kernel<<<(E_TOT + 255) / 256, 256, 0, stream>>>(esrc, edst, cnt8, ssrc);

    gemm1_norm_kernel<<<N_NODES / 16, 256, 0, stream>>>(x, W1, b1, hnA, rA);

    int nblk = N_NODES / 4;   // 5000, exact
    // L0: A -> B, L1: B -> A, L2: A -> B, L3: B -> h0 (fp32)
    agnn_kernel<<<nblk, 256, 0, stream>>>(hnA, rA, indptr, ssrc, perm, hnB, rB, h0, 1);
    agnn_kernel<<<nblk, 256, 0, stream>>>(hnB, rB, indptr, ssrc, perm, hnA, rA, h0, 1);
    agnn_kernel<<<nblk, 256, 0, stream>>>(hnA, rA, indptr, ssrc, perm, hnB, rB, h0, 1);
    agnn_kernel<<<nblk, 256, 0, stream>>>(hnB, rB, indptr, ssrc, perm, hnA, rA, h0, 0);

    dim3 g2((N_NODES + 63) / 64, OUT_DIM / 64);
    gemm_bias_act<<<g2, 256, 0, stream>>>(h0, W2, b2, out, N_NODES, OUT_DIM, HIDDEN, 0);
}

// Round 14
// 322.071 us; speedup vs baseline: 3.2431x; 1.0088x over previous
//
#include <hip/hip_runtime.h>

#define N_NODES 20000
#define N_EDGES 640000
#define E_TOT   (N_EDGES + N_NODES)   /* 660000: edges + self loops */
#define IN_DIM  128
#define HIDDEN  256
#define OUT_DIM 64
#define LOG2E 1.4426950408889634f
#define NSHARD 8
#define ZBLOCKS 625                   /* blocks zeroing cnt8 in the dual-role kernel */

typedef __attribute__((ext_vector_type(2))) float f32x2;

__device__ __forceinline__ unsigned short f2bf(float f) {
    union { float f; unsigned int i; } x; x.f = f;
    unsigned int u = x.i;
    return (unsigned short)((u + 0x7fffu + ((u >> 16) & 1u)) >> 16);  // RTNE
}
__device__ __forceinline__ f32x2 up2(unsigned int p) {   // 2 packed bf16 -> 2 fp32
    f32x2 r;
    r.x = __uint_as_float(p << 16);
    r.y = __uint_as_float(p & 0xffff0000u);
    return r;
}
__device__ __forceinline__ unsigned int pk2(float a, float b) {
    return (unsigned int)f2bf(a) | ((unsigned int)f2bf(b) << 16);
}

// ---------------- CSR build (R9-proven structure; zero folded into gemm1) ----------------

__global__ void count_kernel(const int* __restrict__ edge_dst, int* __restrict__ cnt8) {
    int i = blockIdx.x * blockDim.x + threadIdx.x;
    if (i >= E_TOT) return;
    int shard = blockIdx.x & (NSHARD - 1);
    int d = (i < N_EDGES) ? edge_dst[i] : (i - N_EDGES);   // implicit self-loop tail
    atomicAdd(&cnt8[shard * N_NODES + d], 1);
}

__global__ void sumdeg_kernel(const int* __restrict__ cnt8, int* __restrict__ deg) {
    int i = blockIdx.x * blockDim.x + threadIdx.x;
    if (i >= N_NODES) return;
    int s = 0;
#pragma unroll
    for (int s8 = 0; s8 < NSHARD; s8++) s += cnt8[s8 * N_NODES + i];
    deg[i] = s;
}

__global__ __launch_bounds__(1024) void scan1b_kernel(const int* __restrict__ deg,
                                                      int* __restrict__ indptr) {
    const int T = 1024;
    const int C = (N_NODES + T - 1) / T;   // 20 per thread
    __shared__ int sums[T];
    int t = threadIdx.x;
    int base = t * C;
    int local[C];
    int s = 0;
#pragma unroll
    for (int i = 0; i < C; i++) {
        int idx = base + i;
        int v = (idx < N_NODES) ? deg[idx] : 0;
        local[i] = s;
        s += v;
    }
    sums[t] = s;
    __syncthreads();
    for (int off = 1; off < T; off <<= 1) {
        int v = (t >= off) ? sums[t - off] : 0;
        __syncthreads();
        sums[t] += v;
        __syncthreads();
    }
    int prefix = (t == 0) ? 0 : sums[t - 1];
#pragma unroll
    for (int i = 0; i < C; i++) {
        int idx = base + i;
        if (idx < N_NODES) indptr[idx] = prefix + local[i];
    }
    if (t == T - 1) indptr[N_NODES] = prefix + s;   // == E_TOT
}

__global__ void cursor_kernel(const int* __restrict__ indptr, int* __restrict__ cnt8) {
    int i = blockIdx.x * blockDim.x + threadIdx.x;
    if (i >= N_NODES) return;
    int running = indptr[i];
#pragma unroll
    for (int s8 = 0; s8 < NSHARD; s8++) {
        int c = cnt8[s8 * N_NODES + i];
        cnt8[s8 * N_NODES + i] = running;
        running += c;
    }
}

__global__ void scatter_edges_kernel(const int* __restrict__ edge_src,
                                     const int* __restrict__ edge_dst,
                                     int* __restrict__ cnt8,
                                     int* __restrict__ ssrc) {
    int i = blockIdx.x * blockDim.x + threadIdx.x;
    if (i >= E_TOT) return;
    int shard = blockIdx.x & (NSHARD - 1);
    int d, s;
    if (i < N_EDGES) { d = edge_dst[i]; s = edge_src[i]; }
    else             { d = i - N_EDGES; s = d; }
    int pos = atomicAdd(&cnt8[shard * N_NODES + d], 1);   // absolute cursor
    ssrc[pos] = s;
}

// ---------------- DUAL-ROLE: blocks 0..624 zero cnt8; blocks 625.. do GEMM1+norm ----------
// (Everything is stream-serial, so co-scheduling the independent zero phase here
//  saves one kernel boundary. gemm1 portion is the R9-proven scattered-quad form.)

__global__ __launch_bounds__(256) void zero_gemm1_norm_kernel(int* __restrict__ cnt8,
                                                              const float* __restrict__ A,
                                                              const float* __restrict__ W,
                                                              const float* __restrict__ bias,
                                                              unsigned short* __restrict__ hnb,
                                                              float* __restrict__ r) {
    if (blockIdx.x < ZBLOCKS) {
        int i = blockIdx.x * 256 + threadIdx.x;
        if (i < NSHARD * N_NODES) cnt8[i] = 0;
        return;
    }
    __shared__ float As[16][20];
    __shared__ float Bs[16][260];
    int t = threadIdx.x;
    int row = t >> 4;
    int cg  = t & 15;
    int grow = (blockIdx.x - ZBLOCKS) * 16 + row;
    float4 acc0 = make_float4(0.f, 0.f, 0.f, 0.f);
    float4 acc1 = acc0, acc2 = acc0, acc3 = acc0;

    for (int k0 = 0; k0 < IN_DIM; k0 += 16) {
        As[row][cg] = A[(long)grow * IN_DIM + k0 + cg];
        {
            const float4* src = (const float4*)&W[(long)(k0 + row) * HIDDEN];
#pragma unroll
            for (int j = 0; j < 4; j++)
                *((float4*)&Bs[row][4 * cg + 64 * j]) = src[cg + 16 * j];
        }
        __syncthreads();
#pragma unroll
        for (int kk = 0; kk < 16; kk++) {
            float a = As[row][kk];
            float4 q0 = *((const float4*)&Bs[kk][4 * cg]);
            float4 q1 = *((const float4*)&Bs[kk][4 * cg + 64]);
            float4 q2 = *((const float4*)&Bs[kk][4 * cg + 128]);
            float4 q3 = *((const float4*)&Bs[kk][4 * cg + 192]);
            acc0.x += a * q0.x; acc0.y += a * q0.y; acc0.z += a * q0.z; acc0.w += a * q0.w;
            acc1.x += a * q1.x; acc1.y += a * q1.y; acc1.z += a * q1.z; acc1.w += a * q1.w;
            acc2.x += a * q2.x; acc2.y += a * q2.y; acc2.z += a * q2.z; acc2.w += a * q2.w;
            acc3.x += a * q3.x; acc3.y += a * q3.y; acc3.z += a * q3.z; acc3.w += a * q3.w;
        }
        __syncthreads();
    }

    float ss = 0.f;
    {
        float4 bv = *((const float4*)&bias[4 * cg]);
        acc0.x = fmaxf(acc0.x + bv.x, 0.f); acc0.y = fmaxf(acc0.y + bv.y, 0.f);
        acc0.z = fmaxf(acc0.z + bv.z, 0.f); acc0.w = fmaxf(acc0.w + bv.w, 0.f);
        ss += acc0.x * acc0.x + acc0.y * acc0.y + acc0.z * acc0.z + acc0.w * acc0.w;
    }
    {
        float4 bv = *((const float4*)&bias[4 * cg + 64]);
        acc1.x = fmaxf(acc1.x + bv.x, 0.f); acc1.y = fmaxf(acc1.y + bv.y, 0.f);
        acc1.z = fmaxf(acc1.z + bv.z, 0.f); acc1.w = fmaxf(acc1.w + bv.w, 0.f);
        ss += acc1.x * acc1.x + acc1.y * acc1.y + acc1.z * acc1.z + acc1.w * acc1.w;
    }
    {
        float4 bv = *((const float4*)&bias[4 * cg + 128]);
        acc2.x = fmaxf(acc2.x + bv.x, 0.f); acc2.y = fmaxf(acc2.y + bv.y, 0.f);
        acc2.z = fmaxf(acc2.z + bv.z, 0.f); acc2.w = fmaxf(acc2.w + bv.w, 0.f);
        ss += acc2.x * acc2.x + acc2.y * acc2.y + acc2.z * acc2.z + acc2.w * acc2.w;
    }
    {
        float4 bv = *((const float4*)&bias[4 * cg + 192]);
        acc3.x = fmaxf(acc3.x + bv.x, 0.f); acc3.y = fmaxf(acc3.y + bv.y, 0.f);
        acc3.z = fmaxf(acc3.z + bv.z, 0.f); acc3.w = fmaxf(acc3.w + bv.w, 0.f);
        ss += acc3.x * acc3.x + acc3.y * acc3.y + acc3.z * acc3.z + acc3.w * acc3.w;
    }
    ss += __shfl_xor(ss, 1);
    ss += __shfl_xor(ss, 2);
    ss += __shfl_xor(ss, 4);
    ss += __shfl_xor(ss, 8);      // full row = 16 consecutive lanes
    float rr = sqrtf(ss + 1e-12f);
    float ir = 1.f / rr;
    uint2* dst = (uint2*)(hnb + (long)grow * HIDDEN);
    uint2 o;
    o.x = pk2(acc0.x * ir, acc0.y * ir); o.y = pk2(acc0.z * ir, acc0.w * ir);
    dst[cg]      = o;
    o.x = pk2(acc1.x * ir, acc1.y * ir); o.y = pk2(acc1.z * ir, acc1.w * ir);
    dst[cg + 16] = o;
    o.x = pk2(acc2.x * ir, acc2.y * ir); o.y = pk2(acc2.z * ir, acc2.w * ir);
    dst[cg + 32] = o;
    o.x = pk2(acc3.x * ir, acc3.y * ir); o.y = pk2(acc3.z * ir, acc3.w * ir);
    dst[cg + 48] = o;
    if (cg == 0) r[grow] = rr;
}

// ---------------- fp32 tiled GEMM + bias (GEMM2, R3-proven form) ----------------

__global__ __launch_bounds__(256) void gemm_bias_act(const float* __restrict__ A,
                                                     const float* __restrict__ B,
                                                     const float* __restrict__ bias,
                                                     float* __restrict__ C,
                                                     int M, int Nn, int K, int relu) {
    __shared__ float As[16][65];
    __shared__ float Bs[16][65];
    int tid = threadIdx.x;
    int tx = tid & 15, ty = tid >> 4;
    int row0 = blockIdx.x * 64, col0 = blockIdx.y * 64;
    float acc[4][4] = {};
    for (int k0 = 0; k0 < K; k0 += 16) {
        {
            int r_ = tid >> 2;
            int kq = (tid & 3) * 4;
            int gr = row0 + r_;
            float4 a4 = make_float4(0.f, 0.f, 0.f, 0.f);
            if (gr < M) a4 = *(const float4*)&A[(long)gr * K + k0 + kq];
            As[kq + 0][r_] = a4.x; As[kq + 1][r_] = a4.y;
            As[kq + 2][r_] = a4.z; As[kq + 3][r_] = a4.w;
        }
        {
            int kr = tid >> 4;
            int cq = (tid & 15) * 4;
            float4 b4 = *(const float4*)&B[(long)(k0 + kr) * Nn + col0 + cq];
            Bs[kr][cq + 0] = b4.x; Bs[kr][cq + 1] = b4.y;
            Bs[kr][cq + 2] = b4.z; Bs[kr][cq + 3] = b4.w;
        }
        __syncthreads();
#pragma unroll
        for (int kk = 0; kk < 16; kk++) {
            float a[4], b[4];
#pragma unroll
            for (int i = 0; i < 4; i++) a[i] = As[kk][ty * 4 + i];
#pragma unroll
            for (int j = 0; j < 4; j++) b[j] = Bs[kk][tx * 4 + j];
#pragma unroll
            for (int i = 0; i < 4; i++)
#pragma unroll
                for (int j = 0; j < 4; j++) acc[i][j] += a[i] * b[j];
        }
        __syncthreads();
    }
#pragma unroll
    for (int i = 0; i < 4; i++) {
        int gr = row0 + ty * 4 + i;
        if (gr >= M) continue;
#pragma unroll
        for (int j = 0; j < 4; j++) {
            int gc = col0 + tx * 4 + j;
            float v = acc[i][j] + bias[gc];
            if (relu) v = fmaxf(v, 0.f);
            C[(long)gr * Nn + gc] = v;
        }
    }
}

// ---------------- fused AGNN layer (guarded prefetch, 4-deep row pipeline) ----------------
// ONE node per wave; edge list split across four 16-lane groups. Rows for edges
// i, i+1, i+2 held in registers; index for i+3 in flight. Tests latency- vs
// fill-BW-bound: if BW-bound this is neutral and ~45 us is the floor.

__global__ __launch_bounds__(256) void agnn_kernel(const unsigned short* __restrict__ hnb,
                                                   const float* __restrict__ rin,
                                                   const int* __restrict__ indptr,
                                                   const int* __restrict__ ssrc,
                                                   unsigned short* __restrict__ hnout,
                                                   float* __restrict__ rout,
                                                   float* __restrict__ hout,
                                                   int write_hn) {
    int lane = threadIdx.x & 63;
    int wid  = threadIdx.x >> 6;
    int sub  = lane >> 4;          // which quarter of the edge list (0..3)
    int gl   = lane & 15;          // lane in 16-group
    int node = blockIdx.x * 4 + wid;   // grid exact: 5000*4 = 20000

    const uint4* tab4 = (const uint4*)hnb;   // one uint4 = 8 bf16; row = 32 uint4
    long nb = (long)node * 32 + gl * 2;
    uint4 ha = tab4[nb], hb = tab4[nb + 1];
    f32x2 hd2[8];
    hd2[0] = up2(ha.x) * LOG2E; hd2[1] = up2(ha.y) * LOG2E;
    hd2[2] = up2(ha.z) * LOG2E; hd2[3] = up2(ha.w) * LOG2E;
    hd2[4] = up2(hb.x) * LOG2E; hd2[5] = up2(hb.y) * LOG2E;
    hd2[6] = up2(hb.z) * LOG2E; hd2[7] = up2(hb.w) * LOG2E;

    int beg = indptr[node], end = indptr[node + 1];
    int deg = end - beg;               // >= 1 (self loop)
    int qb  = deg >> 2, rem = deg & 3;
    int cnt = qb + (sub < rem ? 1 : 0);
    int eb  = beg + sub * qb + min(sub, rem);
    int nmax = qb + (rem ? 1 : 0);     // uniform wave loop bound

    f32x2 acc[8];
#pragma unroll
    for (int p = 0; p < 8; p++) acc[p] = (f32x2)0.f;
    float z = 0.f;

    // guarded 4-deep pipeline prologue: rows e0,e1,e2 in regs; index for e3
    int s0 = ssrc[(cnt > 0) ? eb : beg];
    long b0 = (long)s0 * 32 + gl * 2;
    uint4 v0a = tab4[b0], v0b = tab4[b0 + 1];
    float r0 = rin[s0];
    uint4 v1a = v0a, v1b = v0b;        // finite defaults for masked tails
    float r1 = 0.f;
    uint4 v2a = v0a, v2b = v0b;
    float r2 = 0.f;
    int sN = s0;
    if (cnt >= 2) {
        int s1 = ssrc[eb + 1];
        long b1 = (long)s1 * 32 + gl * 2;
        v1a = tab4[b1]; v1b = tab4[b1 + 1];
        r1 = rin[s1];
    }
    if (cnt >= 3) {
        int s2 = ssrc[eb + 2];
        long b2 = (long)s2 * 32 + gl * 2;
        v2a = tab4[b2]; v2b = tab4[b2 + 1];
        r2 = rin[s2];
    }
    if (cnt >= 4) sN = ssrc[eb + 3];

    for (int i = 0; i < nmax; i++) {
        uint4 ca = v0a, cb = v0b;
        float cr = r0;
        v0a = v1a; v0b = v1b; r0 = r1;
        v1a = v2a; v1b = v2b; r1 = r2;
        if (i + 3 < cnt) {             // row load for edge i+3 (group-uniform guard)
            long bn = (long)sN * 32 + gl * 2;
            v2a = tab4[bn]; v2b = tab4[bn + 1];
            r2 = rin[sN];
        }
        if (i + 4 < cnt) sN = ssrc[eb + i + 4];

        f32x2 cf[8];
        cf[0] = up2(ca.x); cf[1] = up2(ca.y); cf[2] = up2(ca.z); cf[3] = up2(ca.w);
        cf[4] = up2(cb.x); cf[5] = up2(cb.y); cf[6] = up2(cb.z); cf[7] = up2(cb.w);
        f32x2 da = cf[0] * hd2[0];
        f32x2 db = cf[1] * hd2[1];
        da += cf[2] * hd2[2];  db += cf[3] * hd2[3];
        da += cf[4] * hd2[4];  db += cf[5] * hd2[5];
        da += cf[6] * hd2[6];  db += cf[7] * hd2[7];
        f32x2 d2 = da + db;
        float d = d2.x + d2.y;
        d += __shfl_xor(d, 1);
        d += __shfl_xor(d, 2);
        d += __shfl_xor(d, 4);
        d += __shfl_xor(d, 8);
        float w = (i < cnt) ? exp2f(d) : 0.f;   // mask tail of shorter streams
        z += w;
        float wr = w * cr;
#pragma unroll
        for (int p = 0; p < 8; p++) acc[p] += cf[p] * wr;
    }

    // merge the 4 partial streams (plain sums -- no max state)
    z += __shfl_xor(z, 16);
    z += __shfl_xor(z, 32);
#pragma unroll
    for (int p = 0; p < 8; p++) {
        acc[p].x += __shfl_xor(acc[p].x, 16);
        acc[p].y += __shfl_xor(acc[p].y, 16);
        acc[p].x += __shfl_xor(acc[p].x, 32);
        acc[p].y += __shfl_xor(acc[p].y, 32);
    }

    float inv = 1.f / z;
    f32x2 o[8];
#pragma unroll
    for (int p = 0; p < 8; p++) {
        f32x2 t = acc[p] * inv;
        t.x = fmaxf(t.x, 0.f);
        t.y = fmaxf(t.y, 0.f);
        o[p] = t;
    }

    if (write_hn) {
        float ss = 0.f;
#pragma unroll
        for (int p = 0; p < 8; p++) ss += o[p].x * o[p].x + o[p].y * o[p].y;
        ss += __shfl_xor(ss, 1);
        ss += __shfl_xor(ss, 2);
        ss += __shfl_xor(ss, 4);
        ss += __shfl_xor(ss, 8);     // full row lives in each 16-lane group
        float rr = sqrtf(ss + 1e-12f);
        float ir = 1.f / rr;
        if (sub == 0) {
            uint4 oa, ob;
            oa.x = pk2(o[0].x * ir, o[0].y * ir);
            oa.y = pk2(o[1].x * ir, o[1].y * ir);
            oa.z = pk2(o[2].x * ir, o[2].y * ir);
            oa.w = pk2(o[3].x * ir, o[3].y * ir);
            ob.x = pk2(o[4].x * ir, o[4].y * ir);
            ob.y = pk2(o[5].x * ir, o[5].y * ir);
            ob.z = pk2(o[6].x * ir, o[6].y * ir);
            ob.w = pk2(o[7].x * ir, o[7].y * ir);
            uint4* outt = (uint4*)hnout;
            outt[nb] = oa;
            outt[nb + 1] = ob;
            if (gl == 0) rout[node] = rr;
        }
    } else {
        if (sub == 0) {
            float4* ho = (float4*)(hout + (long)node * HIDDEN + gl * 16);
            ho[0] = make_float4(o[0].x, o[0].y, o[1].x, o[1].y);
            ho[1] = make_float4(o[2].x, o[2].y, o[3].x, o[3].y);
            ho[2] = make_float4(o[4].x, o[4].y, o[5].x, o[5].y);
            ho[3] = make_float4(o[6].x, o[6].y, o[7].x, o[7].y);
        }
    }
}

// ---------------- launch (11 kernels) ----------------

extern "C" void kernel_launch(void* const* d_in, const int* in_sizes, int n_in,
                              void* d_out, int out_size, void* d_ws, size_t ws_size,
                              hipStream_t stream) {
    const float* x  = (const float*)d_in[0];
    const int* esrc = (const int*)d_in[1];
    const int* edst = (const int*)d_in[2];
    const float* W1 = (const float*)d_in[3];
    const float* b1 = (const float*)d_in[4];
    const float* W2 = (const float*)d_in[5];
    const float* b2 = (const float*)d_in[6];
    float* out = (float*)d_out;

    char* ws = (char*)d_ws;
    float*          h0     = (float*)(ws);                          // 20,480,000 B
    unsigned short* hnA    = (unsigned short*)(ws + 20480000);      // 10,240,000 B
    unsigned short* hnB    = (unsigned short*)(ws + 30720000);      // 10,240,000 B
    float*          rA     = (float*)(ws + 40960000);               // 80,000 B
    float*          rB     = (float*)(ws + 41040000);               // 80,000 B
    int*            indptr = (int*)  (ws + 41120000);               // 80,004 B (pad)
    int*            cnt8   = (int*)  (ws + 41200256);               // 640,000 B
    int*            ssrc   = (int*)  (ws + 41840256);               // 2,640,000 B
    int*            deg    = (int*)  (ws + 44480256);               // 80,000 B

    // K1: zero cnt8 (blocks 0..624) || GEMM1+norm (blocks 625..1874)
    zero_gemm1_norm_kernel<<<ZBLOCKS + N_NODES / 16, 256, 0, stream>>>(
        cnt8, x, W1, b1, hnA, rA);

    count_kernel<<<(E_TOT + 255) / 256, 256, 0, stream>>>(edst, cnt8);
    sumdeg_kernel<<<(N_NODES + 255) / 256, 256, 0, stream>>>(cnt8, deg);
    scan1b_kernel<<<1, 1024, 0, stream>>>(deg, indptr);
    cursor_kernel<<<(N_NODES + 255) / 256, 256, 0, stream>>>(indptr, cnt8);
    scatter_edges_kernel<<<(E_TOT + 255) / 256, 256, 0, stream>>>(esrc, edst, cnt8, ssrc);

    int nblk = N_NODES / 4;   // 5000, exact
    // L0: A -> B, L1: B -> A, L2: A -> B, L3: B -> h0 (fp32)
    agnn_kernel<<<nblk, 256, 0, stream>>>(hnA, rA, indptr, ssrc, hnB, rB, h0, 1);
    agnn_kernel<<<nblk, 256, 0, stream>>>(hnB, rB, indptr, ssrc, hnA, rA, h0, 1);
    agnn_kernel<<<nblk, 256, 0, stream>>>(hnA, rA, indptr, ssrc, hnB, rB, h0, 1);
    agnn_kernel<<<nblk, 256, 0, stream>>>(hnB, rB, indptr, ssrc, hnA, rA, h0, 0);

    dim3 g2((N_NODES + 63) / 64, OUT_DIM / 64);
    gemm_bias_act<<<g2, 256, 0, stream>>>(h0, W2, b2, out, N_NODES, OUT_DIM, HIDDEN, 0);
}

// Round 15
// 304.985 us; speedup vs baseline: 3.4248x; 1.0560x over previous
//
#include <hip/hip_runtime.h>

#define N_NODES 20000
#define N_EDGES 640000
#define E_TOT   (N_EDGES + N_NODES)   /* 660000: edges + self loops */
#define IN_DIM  128
#define HIDDEN  256
#define OUT_DIM 64
#define LOG2E 1.4426950408889634f
#define NSHARD 8
#define ZBLOCKS 625                   /* blocks zeroing cnt8 in the dual-role kernel */

typedef __attribute__((ext_vector_type(2))) float f32x2;

__device__ __forceinline__ unsigned short f2bf(float f) {
    union { float f; unsigned int i; } x; x.f = f;
    unsigned int u = x.i;
    return (unsigned short)((u + 0x7fffu + ((u >> 16) & 1u)) >> 16);  // RTNE
}
__device__ __forceinline__ f32x2 up2(unsigned int p) {   // 2 packed bf16 -> 2 fp32
    f32x2 r;
    r.x = __uint_as_float(p << 16);
    r.y = __uint_as_float(p & 0xffff0000u);
    return r;
}
__device__ __forceinline__ unsigned int pk2(float a, float b) {
    return (unsigned int)f2bf(a) | ((unsigned int)f2bf(b) << 16);
}

// ---------------- CSR build (R9-proven structure; zero folded into gemm1) ----------------

__global__ void count_kernel(const int* __restrict__ edge_dst, int* __restrict__ cnt8) {
    int i = blockIdx.x * blockDim.x + threadIdx.x;
    if (i >= E_TOT) return;
    int shard = blockIdx.x & (NSHARD - 1);
    int d = (i < N_EDGES) ? edge_dst[i] : (i - N_EDGES);   // implicit self-loop tail
    atomicAdd(&cnt8[shard * N_NODES + d], 1);
}

__global__ void sumdeg_kernel(const int* __restrict__ cnt8, int* __restrict__ deg) {
    int i = blockIdx.x * blockDim.x + threadIdx.x;
    if (i >= N_NODES) return;
    int s = 0;
#pragma unroll
    for (int s8 = 0; s8 < NSHARD; s8++) s += cnt8[s8 * N_NODES + i];
    deg[i] = s;
}

__global__ __launch_bounds__(1024) void scan1b_kernel(const int* __restrict__ deg,
                                                      int* __restrict__ indptr) {
    const int T = 1024;
    const int C = (N_NODES + T - 1) / T;   // 20 per thread
    __shared__ int sums[T];
    int t = threadIdx.x;
    int base = t * C;
    int local[C];
    int s = 0;
#pragma unroll
    for (int i = 0; i < C; i++) {
        int idx = base + i;
        int v = (idx < N_NODES) ? deg[idx] : 0;
        local[i] = s;
        s += v;
    }
    sums[t] = s;
    __syncthreads();
    for (int off = 1; off < T; off <<= 1) {
        int v = (t >= off) ? sums[t - off] : 0;
        __syncthreads();
        sums[t] += v;
        __syncthreads();
    }
    int prefix = (t == 0) ? 0 : sums[t - 1];
#pragma unroll
    for (int i = 0; i < C; i++) {
        int idx = base + i;
        if (idx < N_NODES) indptr[idx] = prefix + local[i];
    }
    if (t == T - 1) indptr[N_NODES] = prefix + s;   // == E_TOT
}

__global__ void cursor_kernel(const int* __restrict__ indptr, int* __restrict__ cnt8) {
    int i = blockIdx.x * blockDim.x + threadIdx.x;
    if (i >= N_NODES) return;
    int running = indptr[i];
#pragma unroll
    for (int s8 = 0; s8 < NSHARD; s8++) {
        int c = cnt8[s8 * N_NODES + i];
        cnt8[s8 * N_NODES + i] = running;
        running += c;
    }
}

__global__ void scatter_edges_kernel(const int* __restrict__ edge_src,
                                     const int* __restrict__ edge_dst,
                                     int* __restrict__ cnt8,
                                     int* __restrict__ ssrc) {
    int i = blockIdx.x * blockDim.x + threadIdx.x;
    if (i >= E_TOT) return;
    int shard = blockIdx.x & (NSHARD - 1);
    int d, s;
    if (i < N_EDGES) { d = edge_dst[i]; s = edge_src[i]; }
    else             { d = i - N_EDGES; s = d; }
    int pos = atomicAdd(&cnt8[shard * N_NODES + d], 1);   // absolute cursor
    ssrc[pos] = s;
}

// ---------------- DUAL-ROLE: blocks 0..624 zero cnt8; blocks 625.. do GEMM1+norm ----------

__global__ __launch_bounds__(256) void zero_gemm1_norm_kernel(int* __restrict__ cnt8,
                                                              const float* __restrict__ A,
                                                              const float* __restrict__ W,
                                                              const float* __restrict__ bias,
                                                              unsigned short* __restrict__ hnb,
                                                              float* __restrict__ r) {
    if (blockIdx.x < ZBLOCKS) {
        int i = blockIdx.x * 256 + threadIdx.x;
        if (i < NSHARD * N_NODES) cnt8[i] = 0;
        return;
    }
    __shared__ float As[16][20];
    __shared__ float Bs[16][260];
    int t = threadIdx.x;
    int row = t >> 4;
    int cg  = t & 15;
    int grow = (blockIdx.x - ZBLOCKS) * 16 + row;
    float4 acc0 = make_float4(0.f, 0.f, 0.f, 0.f);
    float4 acc1 = acc0, acc2 = acc0, acc3 = acc0;

    for (int k0 = 0; k0 < IN_DIM; k0 += 16) {
        As[row][cg] = A[(long)grow * IN_DIM + k0 + cg];
        {
            const float4* src = (const float4*)&W[(long)(k0 + row) * HIDDEN];
#pragma unroll
            for (int j = 0; j < 4; j++)
                *((float4*)&Bs[row][4 * cg + 64 * j]) = src[cg + 16 * j];
        }
        __syncthreads();
#pragma unroll
        for (int kk = 0; kk < 16; kk++) {
            float a = As[row][kk];
            float4 q0 = *((const float4*)&Bs[kk][4 * cg]);
            float4 q1 = *((const float4*)&Bs[kk][4 * cg + 64]);
            float4 q2 = *((const float4*)&Bs[kk][4 * cg + 128]);
            float4 q3 = *((const float4*)&Bs[kk][4 * cg + 192]);
            acc0.x += a * q0.x; acc0.y += a * q0.y; acc0.z += a * q0.z; acc0.w += a * q0.w;
            acc1.x += a * q1.x; acc1.y += a * q1.y; acc1.z += a * q1.z; acc1.w += a * q1.w;
            acc2.x += a * q2.x; acc2.y += a * q2.y; acc2.z += a * q2.z; acc2.w += a * q2.w;
            acc3.x += a * q3.x; acc3.y += a * q3.y; acc3.z += a * q3.z; acc3.w += a * q3.w;
        }
        __syncthreads();
    }

    float ss = 0.f;
    {
        float4 bv = *((const float4*)&bias[4 * cg]);
        acc0.x = fmaxf(acc0.x + bv.x, 0.f); acc0.y = fmaxf(acc0.y + bv.y, 0.f);
        acc0.z = fmaxf(acc0.z + bv.z, 0.f); acc0.w = fmaxf(acc0.w + bv.w, 0.f);
        ss += acc0.x * acc0.x + acc0.y * acc0.y + acc0.z * acc0.z + acc0.w * acc0.w;
    }
    {
        float4 bv = *((const float4*)&bias[4 * cg + 64]);
        acc1.x = fmaxf(acc1.x + bv.x, 0.f); acc1.y = fmaxf(acc1.y + bv.y, 0.f);
        acc1.z = fmaxf(acc1.z + bv.z, 0.f); acc1.w = fmaxf(acc1.w + bv.w, 0.f);
        ss += acc1.x * acc1.x + acc1.y * acc1.y + acc1.z * acc1.z + acc1.w * acc1.w;
    }
    {
        float4 bv = *((const float4*)&bias[4 * cg + 128]);
        acc2.x = fmaxf(acc2.x + bv.x, 0.f); acc2.y = fmaxf(acc2.y + bv.y, 0.f);
        acc2.z = fmaxf(acc2.z + bv.z, 0.f); acc2.w = fmaxf(acc2.w + bv.w, 0.f);
        ss += acc2.x * acc2.x + acc2.y * acc2.y + acc2.z * acc2.z + acc2.w * acc2.w;
    }
    {
        float4 bv = *((const float4*)&bias[4 * cg + 192]);
        acc3.x = fmaxf(acc3.x + bv.x, 0.f); acc3.y = fmaxf(acc3.y + bv.y, 0.f);
        acc3.z = fmaxf(acc3.z + bv.z, 0.f); acc3.w = fmaxf(acc3.w + bv.w, 0.f);
        ss += acc3.x * acc3.x + acc3.y * acc3.y + acc3.z * acc3.z + acc3.w * acc3.w;
    }
    ss += __shfl_xor(ss, 1);
    ss += __shfl_xor(ss, 2);
    ss += __shfl_xor(ss, 4);
    ss += __shfl_xor(ss, 8);      // full row = 16 consecutive lanes
    float rr = sqrtf(ss + 1e-12f);
    float ir = 1.f / rr;
    uint2* dst = (uint2*)(hnb + (long)grow * HIDDEN);
    uint2 o;
    o.x = pk2(acc0.x * ir, acc0.y * ir); o.y = pk2(acc0.z * ir, acc0.w * ir);
    dst[cg]      = o;
    o.x = pk2(acc1.x * ir, acc1.y * ir); o.y = pk2(acc1.z * ir, acc1.w * ir);
    dst[cg + 16] = o;
    o.x = pk2(acc2.x * ir, acc2.y * ir); o.y = pk2(acc2.z * ir, acc2.w * ir);
    dst[cg + 32] = o;
    o.x = pk2(acc3.x * ir, acc3.y * ir); o.y = pk2(acc3.z * ir, acc3.w * ir);
    dst[cg + 48] = o;
    if (cg == 0) r[grow] = rr;
}

// ---------------- fp32 tiled GEMM + bias (GEMM2, R3-proven form) ----------------

__global__ __launch_bounds__(256) void gemm_bias_act(const float* __restrict__ A,
                                                     const float* __restrict__ B,
                                                     const float* __restrict__ bias,
                                                     float* __restrict__ C,
                                                     int M, int Nn, int K, int relu) {
    __shared__ float As[16][65];
    __shared__ float Bs[16][65];
    int tid = threadIdx.x;
    int tx = tid & 15, ty = tid >> 4;
    int row0 = blockIdx.x * 64, col0 = blockIdx.y * 64;
    float acc[4][4] = {};
    for (int k0 = 0; k0 < K; k0 += 16) {
        {
            int r_ = tid >> 2;
            int kq = (tid & 3) * 4;
            int gr = row0 + r_;
            float4 a4 = make_float4(0.f, 0.f, 0.f, 0.f);
            if (gr < M) a4 = *(const float4*)&A[(long)gr * K + k0 + kq];
            As[kq + 0][r_] = a4.x; As[kq + 1][r_] = a4.y;
            As[kq + 2][r_] = a4.z; As[kq + 3][r_] = a4.w;
        }
        {
            int kr = tid >> 4;
            int cq = (tid & 15) * 4;
            float4 b4 = *(const float4*)&B[(long)(k0 + kr) * Nn + col0 + cq];
            Bs[kr][cq + 0] = b4.x; Bs[kr][cq + 1] = b4.y;
            Bs[kr][cq + 2] = b4.z; Bs[kr][cq + 3] = b4.w;
        }
        __syncthreads();
#pragma unroll
        for (int kk = 0; kk < 16; kk++) {
            float a[4], b[4];
#pragma unroll
            for (int i = 0; i < 4; i++) a[i] = As[kk][ty * 4 + i];
#pragma unroll
            for (int j = 0; j < 4; j++) b[j] = Bs[kk][tx * 4 + j];
#pragma unroll
            for (int i = 0; i < 4; i++)
#pragma unroll
                for (int j = 0; j < 4; j++) acc[i][j] += a[i] * b[j];
        }
        __syncthreads();
    }
#pragma unroll
    for (int i = 0; i < 4; i++) {
        int gr = row0 + ty * 4 + i;
        if (gr >= M) continue;
#pragma unroll
        for (int j = 0; j < 4; j++) {
            int gc = col0 + tx * 4 + j;
            float v = acc[i][j] + bias[gc];
            if (relu) v = fmaxf(v, 0.f);
            C[(long)gr * Nn + gc] = v;
        }
    }
}

// ---------------- fused AGNN layer (R9-exact: guarded 3-deep prefetch, 48 VGPR) ----------

__global__ __launch_bounds__(256) void agnn_kernel(const unsigned short* __restrict__ hnb,
                                                   const float* __restrict__ rin,
                                                   const int* __restrict__ indptr,
                                                   const int* __restrict__ ssrc,
                                                   unsigned short* __restrict__ hnout,
                                                   float* __restrict__ rout,
                                                   float* __restrict__ hout,
                                                   int write_hn) {
    int lane = threadIdx.x & 63;
    int wid  = threadIdx.x >> 6;
    int sub  = lane >> 4;          // which quarter of the edge list (0..3)
    int gl   = lane & 15;          // lane in 16-group
    int node = blockIdx.x * 4 + wid;   // grid exact: 5000*4 = 20000

    const uint4* tab4 = (const uint4*)hnb;   // one uint4 = 8 bf16; row = 32 uint4
    long nb = (long)node * 32 + gl * 2;
    uint4 ha = tab4[nb], hb = tab4[nb + 1];
    f32x2 hd2[8];
    hd2[0] = up2(ha.x) * LOG2E; hd2[1] = up2(ha.y) * LOG2E;
    hd2[2] = up2(ha.z) * LOG2E; hd2[3] = up2(ha.w) * LOG2E;
    hd2[4] = up2(hb.x) * LOG2E; hd2[5] = up2(hb.y) * LOG2E;
    hd2[6] = up2(hb.z) * LOG2E; hd2[7] = up2(hb.w) * LOG2E;

    int beg = indptr[node], end = indptr[node + 1];
    int deg = end - beg;               // >= 1 (self loop)
    int qb  = deg >> 2, rem = deg & 3;
    int cnt = qb + (sub < rem ? 1 : 0);
    int eb  = beg + sub * qb + min(sub, rem);
    int nmax = qb + (rem ? 1 : 0);     // uniform wave loop bound

    f32x2 acc[8];
#pragma unroll
    for (int p = 0; p < 8; p++) acc[p] = (f32x2)0.f;
    float z = 0.f;

    // guarded 3-deep pipeline prologue
    int s0 = ssrc[(cnt > 0) ? eb : beg];
    long b0 = (long)s0 * 32 + gl * 2;
    uint4 v0a = tab4[b0], v0b = tab4[b0 + 1];
    float r0 = rin[s0];
    uint4 v1a = v0a, v1b = v0b;        // finite defaults for masked tails
    float r1 = 0.f;
    int s2 = s0;
    if (cnt >= 2) {
        int s1 = ssrc[eb + 1];
        long b1 = (long)s1 * 32 + gl * 2;
        v1a = tab4[b1]; v1b = tab4[b1 + 1];
        r1 = rin[s1];
    }
    if (cnt >= 3) s2 = ssrc[eb + 2];

    for (int i = 0; i < nmax; i++) {
        uint4 ca = v0a, cb = v0b;
        float cr = r0;
        v0a = v1a; v0b = v1b; r0 = r1;
        if (i + 2 < cnt) {             // group-uniform guard: no wasted gathers
            long b2 = (long)s2 * 32 + gl * 2;
            v1a = tab4[b2]; v1b = tab4[b2 + 1];
            r1 = rin[s2];
        }
        if (i + 3 < cnt) s2 = ssrc[eb + i + 3];

        f32x2 cf[8];
        cf[0] = up2(ca.x); cf[1] = up2(ca.y); cf[2] = up2(ca.z); cf[3] = up2(ca.w);
        cf[4] = up2(cb.x); cf[5] = up2(cb.y); cf[6] = up2(cb.z); cf[7] = up2(cb.w);
        f32x2 da = cf[0] * hd2[0];
        f32x2 db = cf[1] * hd2[1];
        da += cf[2] * hd2[2];  db += cf[3] * hd2[3];
        da += cf[4] * hd2[4];  db += cf[5] * hd2[5];
        da += cf[6] * hd2[6];  db += cf[7] * hd2[7];
        f32x2 d2 = da + db;
        float d = d2.x + d2.y;
        d += __shfl_xor(d, 1);
        d += __shfl_xor(d, 2);
        d += __shfl_xor(d, 4);
        d += __shfl_xor(d, 8);
        float w = (i < cnt) ? exp2f(d) : 0.f;   // mask tail of shorter streams
        z += w;
        float wr = w * cr;
#pragma unroll
        for (int p = 0; p < 8; p++) acc[p] += cf[p] * wr;
    }

    // merge the 4 partial streams (plain sums -- no max state)
    z += __shfl_xor(z, 16);
    z += __shfl_xor(z, 32);
#pragma unroll
    for (int p = 0; p < 8; p++) {
        acc[p].x += __shfl_xor(acc[p].x, 16);
        acc[p].y += __shfl_xor(acc[p].y, 16);
        acc[p].x += __shfl_xor(acc[p].x, 32);
        acc[p].y += __shfl_xor(acc[p].y, 32);
    }

    float inv = 1.f / z;
    f32x2 o[8];
#pragma unroll
    for (int p = 0; p < 8; p++) {
        f32x2 t = acc[p] * inv;
        t.x = fmaxf(t.x, 0.f);
        t.y = fmaxf(t.y, 0.f);
        o[p] = t;
    }

    if (write_hn) {
        float ss = 0.f;
#pragma unroll
        for (int p = 0; p < 8; p++) ss += o[p].x * o[p].x + o[p].y * o[p].y;
        ss += __shfl_xor(ss, 1);
        ss += __shfl_xor(ss, 2);
        ss += __shfl_xor(ss, 4);
        ss += __shfl_xor(ss, 8);     // full row lives in each 16-lane group
        float rr = sqrtf(ss + 1e-12f);
        float ir = 1.f / rr;
        if (sub == 0) {
            uint4 oa, ob;
            oa.x = pk2(o[0].x * ir, o[0].y * ir);
            oa.y = pk2(o[1].x * ir, o[1].y * ir);
            oa.z = pk2(o[2].x * ir, o[2].y * ir);
            oa.w = pk2(o[3].x * ir, o[3].y * ir);
            ob.x = pk2(o[4].x * ir, o[4].y * ir);
            ob.y = pk2(o[5].x * ir, o[5].y * ir);
            ob.z = pk2(o[6].x * ir, o[6].y * ir);
            ob.w = pk2(o[7].x * ir, o[7].y * ir);
            uint4* outt = (uint4*)hnout;
            outt[nb] = oa;
            outt[nb + 1] = ob;
            if (gl == 0) rout[node] = rr;
        }
    } else {
        if (sub == 0) {
            float4* ho = (float4*)(hout + (long)node * HIDDEN + gl * 16);
            ho[0] = make_float4(o[0].x, o[0].y, o[1].x, o[1].y);
            ho[1] = make_float4(o[2].x, o[2].y, o[3].x, o[3].y);
            ho[2] = make_float4(o[4].x, o[4].y, o[5].x, o[5].y);
            ho[3] = make_float4(o[6].x, o[6].y, o[7].x, o[7].y);
        }
    }
}

// ---------------- launch (11 kernels) ----------------

extern "C" void kernel_launch(void* const* d_in, const int* in_sizes, int n_in,
                              void* d_out, int out_size, void* d_ws, size_t ws_size,
                              hipStream_t stream) {
    const float* x  = (const float*)d_in[0];
    const int* esrc = (const int*)d_in[1];
    const int* edst = (const int*)d_in[2];
    const float* W1 = (const float*)d_in[3];
    const float* b1 = (const float*)d_in[4];
    const float* W2 = (const float*)d_in[5];
    const float* b2 = (const float*)d_in[6];
    float* out = (float*)d_out;

    char* ws = (char*)d_ws;
    float*          h0     = (float*)(ws);                          // 20,480,000 B
    unsigned short* hnA    = (unsigned short*)(ws + 20480000);      // 10,240,000 B
    unsigned short* hnB    = (unsigned short*)(ws + 30720000);      // 10,240,000 B
    float*          rA     = (float*)(ws + 40960000);               // 80,000 B
    float*          rB     = (float*)(ws + 41040000);               // 80,000 B
    int*            indptr = (int*)  (ws + 41120000);               // 80,004 B (pad)
    int*            cnt8   = (int*)  (ws + 41200256);               // 640,000 B
    int*            ssrc   = (int*)  (ws + 41840256);               // 2,640,000 B
    int*            deg    = (int*)  (ws + 44480256);               // 80,000 B

    // K1: zero cnt8 (blocks 0..624) || GEMM1+norm (blocks 625..1874)
    zero_gemm1_norm_kernel<<<ZBLOCKS + N_NODES / 16, 256, 0, stream>>>(
        cnt8, x, W1, b1, hnA, rA);

    count_kernel<<<(E_TOT + 255) / 256, 256, 0, stream>>>(edst, cnt8);
    sumdeg_kernel<<<(N_NODES + 255) / 256, 256, 0, stream>>>(cnt8, deg);
    scan1b_kernel<<<1, 1024, 0, stream>>>(deg, indptr);
    cursor_kernel<<<(N_NODES + 255) / 256, 256, 0, stream>>>(indptr, cnt8);
    scatter_edges_kernel<<<(E_TOT + 255) / 256, 256, 0, stream>>>(esrc, edst, cnt8, ssrc);

    int nblk = N_NODES / 4;   // 5000, exact
    // L0: A -> B, L1: B -> A, L2: A -> B, L3: B -> h0 (fp32)
    agnn_kernel<<<nblk, 256, 0, stream>>>(hnA, rA, indptr, ssrc, hnB, rB, h0, 1);
    agnn_kernel<<<nblk, 256, 0, stream>>>(hnB, rB, indptr, ssrc, hnA, rA, h0, 1);
    agnn_kernel<<<nblk, 256, 0, stream>>>(hnA, rA, indptr, ssrc, hnB, rB, h0, 1);
    agnn_kernel<<<nblk, 256, 0, stream>>>(hnB, rB, indptr, ssrc, hnA, rA, h0, 0);

    dim3 g2((N_NODES + 63) / 64, OUT_DIM / 64);
    gemm_bias_act<<<g2, 256, 0, stream>>>(h0, W2, b2, out, N_NODES, OUT_DIM, HIDDEN, 0);
}